// Round 1
// baseline (1314.853 us; speedup 1.0000x reference)
//
#include <hip/hip_runtime.h>
#include <cmath>

// FAGCN: N=50000 nodes, E=1.6M edges, FEAT=512, HIDDEN=128, CLASS=40, 4 layers, eps=0.3
// Pipeline per call (graph-capture safe, all on `stream`):
//   deg count -> dis=rsqrt(deg+1) -> exclusive scan -> CSR fill (src,dst,norm)
//   GEMM1 (relu(x@W1^T+b1)) -> 4x [dots, edge coef, wave-per-node gather-aggregate]
//   fused logits + log_softmax

#define HIDDEN 128
#define FEAT 512
#define NCLASS 40

// ---------------- degree / dis ----------------
__global__ void k_degree(const int* __restrict__ ei, int E, int* __restrict__ deg) {
    int e = blockIdx.x * 256 + threadIdx.x;
    if (e < E) atomicAdd(&deg[ei[E + e]], 1);   // dst row is second row
}

__global__ void k_dis(const int* __restrict__ deg, float* __restrict__ dis, int n) {
    int i = blockIdx.x * 256 + threadIdx.x;
    if (i < n) dis[i] = rsqrtf((float)(deg[i] + 1));  // +1 self-loop; always >=1
}

// ---------------- exclusive scan (3-kernel) ----------------
__global__ void k_scan1(const int* __restrict__ deg, int* __restrict__ offs,
                        int* __restrict__ part, int n) {
    __shared__ int s[256];
    int tid = threadIdx.x;
    int gid = blockIdx.x * 256 + tid;
    int v = (gid < n) ? deg[gid] : 0;
    s[tid] = v;
    __syncthreads();
    for (int off = 1; off < 256; off <<= 1) {
        int t = (tid >= off) ? s[tid - off] : 0;
        __syncthreads();
        s[tid] += t;
        __syncthreads();
    }
    if (gid < n) offs[gid] = s[tid] - v;          // exclusive
    if (tid == 255) part[blockIdx.x] = s[255];    // block total
}

__global__ void k_scan2(int* __restrict__ part, int nb) {
    __shared__ int s[256];
    int tid = threadIdx.x;
    int v = (tid < nb) ? part[tid] : 0;
    s[tid] = v;
    __syncthreads();
    for (int off = 1; off < 256; off <<= 1) {
        int t = (tid >= off) ? s[tid - off] : 0;
        __syncthreads();
        s[tid] += t;
        __syncthreads();
    }
    if (tid < nb) part[tid] = s[tid] - v;         // exclusive
}

__global__ void k_scan3(int* __restrict__ offs, const int* __restrict__ part, int n, int E) {
    int gid = blockIdx.x * 256 + threadIdx.x;
    if (gid < n) offs[gid] += part[blockIdx.x];
    if (gid == 0) offs[n] = E;
}

// ---------------- CSR fill ----------------
__global__ void k_csr_fill(const int* __restrict__ ei, int E,
                           const int* __restrict__ offs, int* __restrict__ cur,
                           const float* __restrict__ dis,
                           int* __restrict__ csrc, int* __restrict__ cdst,
                           float* __restrict__ cnrm) {
    int e = blockIdx.x * 256 + threadIdx.x;
    if (e >= E) return;
    int src = ei[e];
    int dst = ei[E + e];
    int pos = offs[dst] + atomicAdd(&cur[dst], 1);
    csrc[pos] = src;
    cdst[pos] = dst;
    cnrm[pos] = dis[src] * dis[dst];
}

// ---------------- GEMM1: h = relu(x @ W1^T + b1), also copy to raw -------------
// BM=64, BN=128(all), BK=32; 256 threads; micro-tile 4 rows x 8 cols.
__global__ __launch_bounds__(256) void k_gemm1(const float* __restrict__ x,
                                               const float* __restrict__ W1,
                                               const float* __restrict__ b1,
                                               float* __restrict__ h,
                                               float* __restrict__ raw, int M) {
    __shared__ float xs[64][36];    // pad 36: float4-aligned rows (144B), fewer bank hits
    __shared__ float ws[32][132];   // ws[k][n], pad 132 (528B rows, float4-aligned)
    const int tid = threadIdx.x;
    const int bm = blockIdx.x * 64;
    const int tr = (tid >> 4) * 4;  // 0..60
    const int tc = (tid & 15) * 8;  // 0..120
    float acc[4][8] = {};
    for (int k0 = 0; k0 < FEAT; k0 += 32) {
        // stage x tile: 64x32 = 512 float4, 2 per thread
        for (int i = tid; i < 512; i += 256) {
            int r = i >> 3, kk = (i & 7) << 2;
            int row = bm + r;
            float4 v = make_float4(0.f, 0.f, 0.f, 0.f);
            if (row < M) v = *(const float4*)(x + (size_t)row * FEAT + k0 + kk);
            *(float4*)&xs[r][kk] = v;
        }
        // stage W1 tile transposed: 128x32 = 1024 float4, 4 per thread
        for (int i = tid; i < 1024; i += 256) {
            int c = i >> 3, kk = (i & 7) << 2;
            float4 v = *(const float4*)(W1 + (size_t)c * FEAT + k0 + kk);
            ws[kk + 0][c] = v.x;
            ws[kk + 1][c] = v.y;
            ws[kk + 2][c] = v.z;
            ws[kk + 3][c] = v.w;
        }
        __syncthreads();
#pragma unroll
        for (int kk = 0; kk < 32; ++kk) {
            float aa[4];
#pragma unroll
            for (int r = 0; r < 4; ++r) aa[r] = xs[tr + r][kk];
            float4 bv0 = *(const float4*)&ws[kk][tc];
            float4 bv1 = *(const float4*)&ws[kk][tc + 4];
            float bb[8] = {bv0.x, bv0.y, bv0.z, bv0.w, bv1.x, bv1.y, bv1.z, bv1.w};
#pragma unroll
            for (int r = 0; r < 4; ++r)
#pragma unroll
                for (int c = 0; c < 8; ++c) acc[r][c] += aa[r] * bb[c];
        }
        __syncthreads();
    }
#pragma unroll
    for (int r = 0; r < 4; ++r) {
        int row = bm + tr + r;
        if (row >= M) break;
#pragma unroll
        for (int c = 0; c < 8; ++c) {
            float v = acc[r][c] + b1[tc + c];
            v = fmaxf(v, 0.f);
            h[(size_t)row * HIDDEN + tc + c] = v;
            raw[(size_t)row * HIDDEN + tc + c] = v;
        }
    }
}

// ---------------- per-node attention dots: al = h.att_l, ar = h.att_r ----------
// one wave per node, float2 per lane
__global__ void k_dots(const float* __restrict__ h, const float* __restrict__ attl,
                       const float* __restrict__ attr, float* __restrict__ al,
                       float* __restrict__ ar, int n) {
    int node = (blockIdx.x * blockDim.x + threadIdx.x) >> 6;
    int lane = threadIdx.x & 63;
    if (node >= n) return;
    float2 hv = ((const float2*)(h + (size_t)node * HIDDEN))[lane];
    float pl = hv.x * attl[2 * lane] + hv.y * attl[2 * lane + 1];
    float pr = hv.x * attr[2 * lane] + hv.y * attr[2 * lane + 1];
    for (int off = 32; off; off >>= 1) {
        pl += __shfl_down(pl, off);
        pr += __shfl_down(pr, off);
    }
    if (lane == 0) {
        al[node] = pl;
        ar[node] = pr;
    }
}

// ---------------- edge coefficients: coef = tanh(al[s]+ar[d]) * norm ------------
__global__ void k_coef(const int* __restrict__ csrc, const int* __restrict__ cdst,
                       const float* __restrict__ cnrm, const float* __restrict__ al,
                       const float* __restrict__ ar, float* __restrict__ coef, int E) {
    int e = blockIdx.x * 256 + threadIdx.x;
    if (e < E) {
        int s = csrc[e], d = cdst[e];
        coef[e] = tanhf(al[s] + ar[d]) * cnrm[e];
    }
}

// ---------------- aggregate: hout = sum_in coef*h[src] + selfloop + eps*raw -----
// one wave per node; lane holds float2 of the 128-wide feature row
__global__ void k_aggregate(const float* __restrict__ h, const float* __restrict__ raw,
                            const float* __restrict__ al, const float* __restrict__ ar,
                            const float* __restrict__ dis, const int* __restrict__ offs,
                            const int* __restrict__ csrc, const float* __restrict__ coef,
                            float* __restrict__ hout, int n) {
    int node = (blockIdx.x * blockDim.x + threadIdx.x) >> 6;
    int lane = threadIdx.x & 63;
    if (node >= n) return;
    float accx = 0.f, accy = 0.f;
    int e0 = offs[node], e1 = offs[node + 1];
    for (int e = e0; e < e1; ++e) {
        int s = csrc[e];
        float c = coef[e];
        float2 hv = ((const float2*)(h + (size_t)s * HIDDEN))[lane];
        accx += c * hv.x;
        accy += c * hv.y;
    }
    // self loop: norm = dis^2
    {
        float di = dis[node];
        float c = tanhf(al[node] + ar[node]) * di * di;
        float2 hv = ((const float2*)(h + (size_t)node * HIDDEN))[lane];
        accx += c * hv.x;
        accy += c * hv.y;
    }
    float2 rv = ((const float2*)(raw + (size_t)node * HIDDEN))[lane];
    float2 o;
    o.x = accx + 0.3f * rv.x;
    o.y = accy + 0.3f * rv.y;
    ((float2*)(hout + (size_t)node * HIDDEN))[lane] = o;
}

// ---------------- output: log_softmax(h @ W2^T + b2) ---------------------------
// one 64-thread block per node; lanes 0..39 each compute one class
__global__ void k_out(const float* __restrict__ h, const float* __restrict__ W2,
                      const float* __restrict__ b2, float* __restrict__ out, int n) {
    int node = blockIdx.x;
    int lane = threadIdx.x;
    __shared__ float hs[HIDDEN];
    ((float2*)hs)[lane] = ((const float2*)(h + (size_t)node * HIDDEN))[lane];
    __syncthreads();
    float y = -INFINITY;
    if (lane < NCLASS) {
        y = b2[lane];
        const float* w = W2 + (size_t)lane * HIDDEN;
#pragma unroll 8
        for (int k = 0; k < HIDDEN; ++k) y += w[k] * hs[k];
    }
    float m = y;
    for (int off = 32; off; off >>= 1) m = fmaxf(m, __shfl_xor(m, off));
    float ex = (lane < NCLASS) ? expf(y - m) : 0.f;
    float ssum = ex;
    for (int off = 32; off; off >>= 1) ssum += __shfl_xor(ssum, off);
    float lse = m + logf(ssum);
    if (lane < NCLASS) out[(size_t)node * NCLASS + lane] = y - lse;
}

extern "C" void kernel_launch(void* const* d_in, const int* in_sizes, int n_in,
                              void* d_out, int out_size, void* d_ws, size_t ws_size,
                              hipStream_t stream) {
    const float* x    = (const float*)d_in[0];
    const int*   ei   = (const int*)d_in[1];
    const float* W1   = (const float*)d_in[2];
    const float* b1   = (const float*)d_in[3];
    const float* W2   = (const float*)d_in[4];
    const float* b2   = (const float*)d_in[5];
    const float* attl = (const float*)d_in[6];
    const float* attr = (const float*)d_in[7];
    const int N = in_sizes[0] / FEAT;
    const int E = in_sizes[1] / 2;
    float* out = (float*)d_out;

    char* p = (char*)d_ws;
    auto take = [&](size_t bytes) {
        void* q = (void*)p;
        p += (bytes + 255) & ~(size_t)255;
        return q;
    };
    float* h0   = (float*)take((size_t)N * HIDDEN * 4);
    float* h1   = (float*)take((size_t)N * HIDDEN * 4);
    float* raw  = (float*)take((size_t)N * HIDDEN * 4);
    int*   deg  = (int*)take((size_t)N * 4);
    float* dis  = (float*)take((size_t)N * 4);
    int*   offs = (int*)take((size_t)(N + 1) * 4);
    int*   cur  = (int*)take((size_t)N * 4);
    int*   csrc = (int*)take((size_t)E * 4);
    int*   cdst = (int*)take((size_t)E * 4);
    float* cnrm = (float*)take((size_t)E * 4);
    float* coef = (float*)take((size_t)E * 4);
    float* al   = (float*)take((size_t)N * 4);
    float* ar   = (float*)take((size_t)N * 4);
    int*   part = (int*)take(1024);

    hipMemsetAsync(deg, 0, (size_t)N * 4, stream);
    hipMemsetAsync(cur, 0, (size_t)N * 4, stream);

    const int ebl = (E + 255) / 256;
    const int nbl = (N + 255) / 256;   // 196 <= 256 (scan2 capacity)

    k_degree<<<ebl, 256, 0, stream>>>(ei, E, deg);
    k_dis<<<nbl, 256, 0, stream>>>(deg, dis, N);
    k_scan1<<<nbl, 256, 0, stream>>>(deg, offs, part, N);
    k_scan2<<<1, 256, 0, stream>>>(part, nbl);
    k_scan3<<<nbl, 256, 0, stream>>>(offs, part, N, E);
    k_csr_fill<<<ebl, 256, 0, stream>>>(ei, E, offs, cur, dis, csrc, cdst, cnrm);

    k_gemm1<<<(N + 63) / 64, 256, 0, stream>>>(x, W1, b1, h0, raw, N);

    float* hin = h0;
    float* hout = h1;
    for (int l = 0; l < 4; ++l) {
        k_dots<<<(N + 3) / 4, 256, 0, stream>>>(hin, attl + l * HIDDEN, attr + l * HIDDEN,
                                                al, ar, N);
        k_coef<<<ebl, 256, 0, stream>>>(csrc, cdst, cnrm, al, ar, coef, E);
        k_aggregate<<<(N + 3) / 4, 256, 0, stream>>>(hin, raw, al, ar, dis, offs, csrc,
                                                     coef, hout, N);
        float* t = hin; hin = hout; hout = t;
    }

    k_out<<<N, 64, 0, stream>>>(hin, W2, b2, out, N);
}

// Round 2
// 920.191 us; speedup vs baseline: 1.4289x; 1.4289x over previous
//
#include <hip/hip_runtime.h>
#include <cmath>

// FAGCN: N=50000 nodes, E=1.6M edges, FEAT=512, HIDDEN=128, CLASS=40, 4 layers, eps=0.3
// R2: bf16 packed h for the edge gather (halves L2-miss bytes), {src,coef} packed
// edge records, edge-loop unroll x4, dots fused into aggregate epilogue.

#define HIDDEN 128
#define FEAT 512
#define NCLASS 40

__device__ __forceinline__ float bf_lo(unsigned u) { return __uint_as_float(u << 16); }
__device__ __forceinline__ float bf_hi(unsigned u) { return __uint_as_float(u & 0xffff0000u); }
__device__ __forceinline__ unsigned pack_bf16(float x, float y) {
    unsigned ux = __float_as_uint(x);
    unsigned uy = __float_as_uint(y);
    unsigned lx = (ux + 0x7fffu + ((ux >> 16) & 1u)) >> 16;
    unsigned hy = (uy + 0x7fffu + ((uy >> 16) & 1u)) & 0xffff0000u;
    return hy | lx;
}

// ---------------- degree / dis ----------------
__global__ void k_degree(const int* __restrict__ ei, int E, int* __restrict__ deg) {
    int e = blockIdx.x * 256 + threadIdx.x;
    if (e < E) atomicAdd(&deg[ei[E + e]], 1);
}

__global__ void k_dis(const int* __restrict__ deg, float* __restrict__ dis, int n) {
    int i = blockIdx.x * 256 + threadIdx.x;
    if (i < n) dis[i] = rsqrtf((float)(deg[i] + 1));
}

// ---------------- exclusive scan (3-kernel) ----------------
__global__ void k_scan1(const int* __restrict__ deg, int* __restrict__ offs,
                        int* __restrict__ part, int n) {
    __shared__ int s[256];
    int tid = threadIdx.x;
    int gid = blockIdx.x * 256 + tid;
    int v = (gid < n) ? deg[gid] : 0;
    s[tid] = v;
    __syncthreads();
    for (int off = 1; off < 256; off <<= 1) {
        int t = (tid >= off) ? s[tid - off] : 0;
        __syncthreads();
        s[tid] += t;
        __syncthreads();
    }
    if (gid < n) offs[gid] = s[tid] - v;
    if (tid == 255) part[blockIdx.x] = s[255];
}

__global__ void k_scan2(int* __restrict__ part, int nb) {
    __shared__ int s[256];
    int tid = threadIdx.x;
    int v = (tid < nb) ? part[tid] : 0;
    s[tid] = v;
    __syncthreads();
    for (int off = 1; off < 256; off <<= 1) {
        int t = (tid >= off) ? s[tid - off] : 0;
        __syncthreads();
        s[tid] += t;
        __syncthreads();
    }
    if (tid < nb) part[tid] = s[tid] - v;
}

__global__ void k_scan3(int* __restrict__ offs, const int* __restrict__ part, int n, int E) {
    int gid = blockIdx.x * 256 + threadIdx.x;
    if (gid < n) offs[gid] += part[blockIdx.x];
    if (gid == 0) offs[n] = E;
}

// ---------------- CSR fill ----------------
__global__ void k_csr_fill(const int* __restrict__ ei, int E,
                           const int* __restrict__ offs, int* __restrict__ cur,
                           const float* __restrict__ dis,
                           int* __restrict__ csrc, int* __restrict__ cdst,
                           float* __restrict__ cnrm) {
    int e = blockIdx.x * 256 + threadIdx.x;
    if (e >= E) return;
    int src = ei[e];
    int dst = ei[E + e];
    int pos = offs[dst] + atomicAdd(&cur[dst], 1);
    csrc[pos] = src;
    cdst[pos] = dst;
    cnrm[pos] = dis[src] * dis[dst];
}

// ---------------- GEMM1: h = relu(x @ W1^T + b1) -> h fp32, hbf bf16, raw ------
__global__ __launch_bounds__(256) void k_gemm1(const float* __restrict__ x,
                                               const float* __restrict__ W1,
                                               const float* __restrict__ b1,
                                               float* __restrict__ h,
                                               unsigned* __restrict__ hbf,
                                               float* __restrict__ raw, int M) {
    __shared__ float xs[64][36];
    __shared__ float ws[32][132];
    const int tid = threadIdx.x;
    const int bm = blockIdx.x * 64;
    const int tr = (tid >> 4) * 4;
    const int tc = (tid & 15) * 8;
    float acc[4][8] = {};
    for (int k0 = 0; k0 < FEAT; k0 += 32) {
        for (int i = tid; i < 512; i += 256) {
            int r = i >> 3, kk = (i & 7) << 2;
            int row = bm + r;
            float4 v = make_float4(0.f, 0.f, 0.f, 0.f);
            if (row < M) v = *(const float4*)(x + (size_t)row * FEAT + k0 + kk);
            *(float4*)&xs[r][kk] = v;
        }
        for (int i = tid; i < 1024; i += 256) {
            int c = i >> 3, kk = (i & 7) << 2;
            float4 v = *(const float4*)(W1 + (size_t)c * FEAT + k0 + kk);
            ws[kk + 0][c] = v.x;
            ws[kk + 1][c] = v.y;
            ws[kk + 2][c] = v.z;
            ws[kk + 3][c] = v.w;
        }
        __syncthreads();
#pragma unroll
        for (int kk = 0; kk < 32; ++kk) {
            float aa[4];
#pragma unroll
            for (int r = 0; r < 4; ++r) aa[r] = xs[tr + r][kk];
            float4 bv0 = *(const float4*)&ws[kk][tc];
            float4 bv1 = *(const float4*)&ws[kk][tc + 4];
            float bb[8] = {bv0.x, bv0.y, bv0.z, bv0.w, bv1.x, bv1.y, bv1.z, bv1.w};
#pragma unroll
            for (int r = 0; r < 4; ++r)
#pragma unroll
                for (int c = 0; c < 8; ++c) acc[r][c] += aa[r] * bb[c];
        }
        __syncthreads();
    }
#pragma unroll
    for (int r = 0; r < 4; ++r) {
        int row = bm + tr + r;
        if (row >= M) break;
        float v[8];
#pragma unroll
        for (int c = 0; c < 8; ++c) {
            v[c] = fmaxf(acc[r][c] + b1[tc + c], 0.f);
            h[(size_t)row * HIDDEN + tc + c] = v[c];
            raw[(size_t)row * HIDDEN + tc + c] = v[c];
        }
        unsigned pk[4];
#pragma unroll
        for (int c = 0; c < 4; ++c) pk[c] = pack_bf16(v[2 * c], v[2 * c + 1]);
        *(uint4*)(hbf + (size_t)row * 64 + (tc >> 1)) = make_uint4(pk[0], pk[1], pk[2], pk[3]);
    }
}

// ---------------- layer-0 dots ----------------
__global__ void k_dots(const float* __restrict__ h, const float* __restrict__ attl,
                       const float* __restrict__ attr, float* __restrict__ al,
                       float* __restrict__ ar, int n) {
    int node = (blockIdx.x * blockDim.x + threadIdx.x) >> 6;
    int lane = threadIdx.x & 63;
    if (node >= n) return;
    float2 hv = ((const float2*)(h + (size_t)node * HIDDEN))[lane];
    float pl = hv.x * attl[2 * lane] + hv.y * attl[2 * lane + 1];
    float pr = hv.x * attr[2 * lane] + hv.y * attr[2 * lane + 1];
    for (int off = 32; off; off >>= 1) {
        pl += __shfl_down(pl, off);
        pr += __shfl_down(pr, off);
    }
    if (lane == 0) {
        al[node] = pl;
        ar[node] = pr;
    }
}

// ---------------- edge records: ep = {src, tanh(al[s]+ar[d])*norm} --------------
__global__ void k_coef(const int* __restrict__ csrc, const int* __restrict__ cdst,
                       const float* __restrict__ cnrm, const float* __restrict__ al,
                       const float* __restrict__ ar, int2* __restrict__ ep, int E) {
    int e = blockIdx.x * 256 + threadIdx.x;
    if (e < E) {
        int s = csrc[e], d = cdst[e];
        float c = tanhf(al[s] + ar[d]) * cnrm[e];
        ep[e] = make_int2(s, __float_as_int(c));
    }
}

// ---------------- aggregate (bf16 gather) + fused next-layer dots ---------------
__global__ void k_aggregate(const unsigned* __restrict__ hbf, const float* __restrict__ hin,
                            const float* __restrict__ raw, const float* __restrict__ al,
                            const float* __restrict__ ar, const float* __restrict__ dis,
                            const int* __restrict__ offs, const int2* __restrict__ ep,
                            float* __restrict__ hout, unsigned* __restrict__ houtbf,
                            const float* __restrict__ attl_n, const float* __restrict__ attr_n,
                            float* __restrict__ al_o, float* __restrict__ ar_o, int n) {
    int node = (blockIdx.x * blockDim.x + threadIdx.x) >> 6;
    int lane = threadIdx.x & 63;
    if (node >= n) return;
    float ax = 0.f, ay = 0.f;
    int e0 = offs[node], e1 = offs[node + 1];
    int e = e0;
    for (; e + 4 <= e1; e += 4) {
        int2 p0 = ep[e], p1 = ep[e + 1], p2 = ep[e + 2], p3 = ep[e + 3];
        unsigned r0 = hbf[(size_t)p0.x * 64 + lane];
        unsigned r1 = hbf[(size_t)p1.x * 64 + lane];
        unsigned r2 = hbf[(size_t)p2.x * 64 + lane];
        unsigned r3 = hbf[(size_t)p3.x * 64 + lane];
        float c0 = __int_as_float(p0.y), c1 = __int_as_float(p1.y);
        float c2 = __int_as_float(p2.y), c3 = __int_as_float(p3.y);
        ax += c0 * bf_lo(r0); ay += c0 * bf_hi(r0);
        ax += c1 * bf_lo(r1); ay += c1 * bf_hi(r1);
        ax += c2 * bf_lo(r2); ay += c2 * bf_hi(r2);
        ax += c3 * bf_lo(r3); ay += c3 * bf_hi(r3);
    }
    for (; e < e1; ++e) {
        int2 p = ep[e];
        unsigned r = hbf[(size_t)p.x * 64 + lane];
        float c = __int_as_float(p.y);
        ax += c * bf_lo(r);
        ay += c * bf_hi(r);
    }
    // self loop (fp32 row, norm = dis^2)
    {
        float di = dis[node];
        float c = tanhf(al[node] + ar[node]) * di * di;
        float2 hv = ((const float2*)(hin + (size_t)node * HIDDEN))[lane];
        ax += c * hv.x;
        ay += c * hv.y;
    }
    float2 rv = ((const float2*)(raw + (size_t)node * HIDDEN))[lane];
    float ox = ax + 0.3f * rv.x;
    float oy = ay + 0.3f * rv.y;
    ((float2*)(hout + (size_t)node * HIDDEN))[lane] = make_float2(ox, oy);
    houtbf[(size_t)node * 64 + lane] = pack_bf16(ox, oy);
    if (attl_n) {  // fused dots for next layer
        float pl = ox * attl_n[2 * lane] + oy * attl_n[2 * lane + 1];
        float pr = ox * attr_n[2 * lane] + oy * attr_n[2 * lane + 1];
        for (int off = 32; off; off >>= 1) {
            pl += __shfl_down(pl, off);
            pr += __shfl_down(pr, off);
        }
        if (lane == 0) {
            al_o[node] = pl;
            ar_o[node] = pr;
        }
    }
}

// ---------------- output: log_softmax(h @ W2^T + b2) ---------------------------
__global__ void k_out(const float* __restrict__ h, const float* __restrict__ W2,
                      const float* __restrict__ b2, float* __restrict__ out, int n) {
    int node = blockIdx.x;
    int lane = threadIdx.x;
    __shared__ float hs[HIDDEN];
    ((float2*)hs)[lane] = ((const float2*)(h + (size_t)node * HIDDEN))[lane];
    __syncthreads();
    float y = -INFINITY;
    if (lane < NCLASS) {
        y = b2[lane];
        const float* w = W2 + (size_t)lane * HIDDEN;
#pragma unroll 8
        for (int k = 0; k < HIDDEN; ++k) y += w[k] * hs[k];
    }
    float m = y;
    for (int off = 32; off; off >>= 1) m = fmaxf(m, __shfl_xor(m, off));
    float ex = (lane < NCLASS) ? expf(y - m) : 0.f;
    float ssum = ex;
    for (int off = 32; off; off >>= 1) ssum += __shfl_xor(ssum, off);
    float lse = m + logf(ssum);
    if (lane < NCLASS) out[(size_t)node * NCLASS + lane] = y - lse;
}

extern "C" void kernel_launch(void* const* d_in, const int* in_sizes, int n_in,
                              void* d_out, int out_size, void* d_ws, size_t ws_size,
                              hipStream_t stream) {
    const float* x    = (const float*)d_in[0];
    const int*   ei   = (const int*)d_in[1];
    const float* W1   = (const float*)d_in[2];
    const float* b1   = (const float*)d_in[3];
    const float* W2   = (const float*)d_in[4];
    const float* b2   = (const float*)d_in[5];
    const float* attl = (const float*)d_in[6];
    const float* attr = (const float*)d_in[7];
    const int N = in_sizes[0] / FEAT;
    const int E = in_sizes[1] / 2;
    float* out = (float*)d_out;

    char* p = (char*)d_ws;
    auto take = [&](size_t bytes) {
        void* q = (void*)p;
        p += (bytes + 255) & ~(size_t)255;
        return q;
    };
    float*    h0   = (float*)take((size_t)N * HIDDEN * 4);
    float*    h1   = (float*)take((size_t)N * HIDDEN * 4);
    unsigned* hb0  = (unsigned*)take((size_t)N * 64 * 4);
    unsigned* hb1  = (unsigned*)take((size_t)N * 64 * 4);
    float*    raw  = (float*)take((size_t)N * HIDDEN * 4);
    int*      deg  = (int*)take((size_t)N * 4);
    float*    dis  = (float*)take((size_t)N * 4);
    int*      offs = (int*)take((size_t)(N + 1) * 4);
    int*      cur  = (int*)take((size_t)N * 4);
    int*      csrc = (int*)take((size_t)E * 4);
    int*      cdst = (int*)take((size_t)E * 4);
    float*    cnrm = (float*)take((size_t)E * 4);
    int2*     ep   = (int2*)take((size_t)E * 8);
    float*    al   = (float*)take((size_t)N * 4);
    float*    ar   = (float*)take((size_t)N * 4);
    int*      part = (int*)take(1024);

    hipMemsetAsync(deg, 0, (size_t)N * 4, stream);
    hipMemsetAsync(cur, 0, (size_t)N * 4, stream);

    const int ebl = (E + 255) / 256;
    const int nbl = (N + 255) / 256;

    k_degree<<<ebl, 256, 0, stream>>>(ei, E, deg);
    k_dis<<<nbl, 256, 0, stream>>>(deg, dis, N);
    k_scan1<<<nbl, 256, 0, stream>>>(deg, offs, part, N);
    k_scan2<<<1, 256, 0, stream>>>(part, nbl);
    k_scan3<<<nbl, 256, 0, stream>>>(offs, part, N, E);
    k_csr_fill<<<ebl, 256, 0, stream>>>(ei, E, offs, cur, dis, csrc, cdst, cnrm);

    k_gemm1<<<(N + 63) / 64, 256, 0, stream>>>(x, W1, b1, h0, hb0, raw, N);
    k_dots<<<(N + 3) / 4, 256, 0, stream>>>(h0, attl, attr, al, ar, N);

    float*    hin = h0,  *hout = h1;
    unsigned* hbin = hb0, *hbout = hb1;
    for (int l = 0; l < 4; ++l) {
        k_coef<<<ebl, 256, 0, stream>>>(csrc, cdst, cnrm, al, ar, ep, E);
        const float* attl_n = (l < 3) ? (attl + (l + 1) * HIDDEN) : nullptr;
        const float* attr_n = (l < 3) ? (attr + (l + 1) * HIDDEN) : nullptr;
        k_aggregate<<<(N + 3) / 4, 256, 0, stream>>>(hbin, hin, raw, al, ar, dis, offs, ep,
                                                     hout, hbout, attl_n, attr_n, al, ar, N);
        float* t = hin; hin = hout; hout = t;
        unsigned* tb = hbin; hbin = hbout; hbout = tb;
    }

    k_out<<<N, 64, 0, stream>>>(hin, W2, b2, out, N);
}

// Round 3
// 823.639 us; speedup vs baseline: 1.5964x; 1.1172x over previous
//
#include <hip/hip_runtime.h>
#include <cmath>

// FAGCN: N=50000, E=1.6M, FEAT=512, HIDDEN=128, CLASS=40, 4 layers, eps=0.3
// R3: MFMA bf16 GEMM1 (fused fp32->bf16 staging), 4-rows-per-instruction gather
// (16 lanes x 16B) with cross-group shuffle reduction, raw array eliminated.

#define HIDDEN 128
#define FEAT 512
#define NCLASS 40
#define LDST 40  // LDS row stride in ushorts (80 B, 16B-aligned, conflict-reducing pad)

typedef __attribute__((ext_vector_type(8))) short short8;
typedef __attribute__((ext_vector_type(4))) float f32x4;

__device__ __forceinline__ float bf_lo(unsigned u) { return __uint_as_float(u << 16); }
__device__ __forceinline__ float bf_hi(unsigned u) { return __uint_as_float(u & 0xffff0000u); }
__device__ __forceinline__ unsigned pack_bf16(float x, float y) {
    unsigned ux = __float_as_uint(x);
    unsigned uy = __float_as_uint(y);
    unsigned lx = (ux + 0x7fffu + ((ux >> 16) & 1u)) >> 16;
    unsigned hy = (uy + 0x7fffu + ((uy >> 16) & 1u)) & 0xffff0000u;
    return hy | lx;
}

// ---------------- degree / dis ----------------
__global__ void k_degree(const int* __restrict__ ei, int E, int* __restrict__ deg) {
    int e = blockIdx.x * 256 + threadIdx.x;
    if (e < E) atomicAdd(&deg[ei[E + e]], 1);
}

__global__ void k_dis(const int* __restrict__ deg, float* __restrict__ dis, int n) {
    int i = blockIdx.x * 256 + threadIdx.x;
    if (i < n) dis[i] = rsqrtf((float)(deg[i] + 1));
}

// ---------------- exclusive scan ----------------
__global__ void k_scan1(const int* __restrict__ deg, int* __restrict__ offs,
                        int* __restrict__ part, int n) {
    __shared__ int s[256];
    int tid = threadIdx.x;
    int gid = blockIdx.x * 256 + tid;
    int v = (gid < n) ? deg[gid] : 0;
    s[tid] = v;
    __syncthreads();
    for (int off = 1; off < 256; off <<= 1) {
        int t = (tid >= off) ? s[tid - off] : 0;
        __syncthreads();
        s[tid] += t;
        __syncthreads();
    }
    if (gid < n) offs[gid] = s[tid] - v;
    if (tid == 255) part[blockIdx.x] = s[255];
}

__global__ void k_scan2(int* __restrict__ part, int nb) {
    __shared__ int s[256];
    int tid = threadIdx.x;
    int v = (tid < nb) ? part[tid] : 0;
    s[tid] = v;
    __syncthreads();
    for (int off = 1; off < 256; off <<= 1) {
        int t = (tid >= off) ? s[tid - off] : 0;
        __syncthreads();
        s[tid] += t;
        __syncthreads();
    }
    if (tid < nb) part[tid] = s[tid] - v;
}

__global__ void k_scan3(int* __restrict__ offs, const int* __restrict__ part, int n, int E) {
    int gid = blockIdx.x * 256 + threadIdx.x;
    if (gid < n) offs[gid] += part[blockIdx.x];
    if (gid == 0) offs[n] = E;
}

// ---------------- CSR fill ----------------
__global__ void k_csr_fill(const int* __restrict__ ei, int E,
                           const int* __restrict__ offs, int* __restrict__ cur,
                           const float* __restrict__ dis,
                           int* __restrict__ csrc, int* __restrict__ cdst,
                           float* __restrict__ cnrm) {
    int e = blockIdx.x * 256 + threadIdx.x;
    if (e >= E) return;
    int src = ei[e];
    int dst = ei[E + e];
    int pos = offs[dst] + atomicAdd(&cur[dst], 1);
    csrc[pos] = src;
    cdst[pos] = dst;
    cnrm[pos] = dis[src] * dis[dst];
}

// ---------------- GEMM1: h = relu(x @ W1^T + b1), MFMA bf16 -------------------
// 128x128 tile, BK=32, 4 waves each owning a 64x64 quadrant (4x4 16x16x32 tiles).
__global__ __launch_bounds__(256) void k_gemm1(const float* __restrict__ x,
                                               const float* __restrict__ W1,
                                               const float* __restrict__ b1,
                                               float* __restrict__ h, int M) {
    __shared__ ushort As[128 * LDST];
    __shared__ ushort Bs[128 * LDST];
    const int tid = threadIdx.x;
    const int bm = blockIdx.x * 128;
    const int wave = tid >> 6, lane = tid & 63;
    const int rh = (wave >> 1) * 64;  // wave row quadrant
    const int ch = (wave & 1) * 64;   // wave col quadrant
    const int sub = lane & 15, quad = lane >> 4;
    const int lrow = tid >> 3;        // 0..31 (staging)
    const int lcol = (tid & 7) * 4;   // 0..28 (staging, float idx)
    f32x4 acc[4][4] = {};
    for (int k0 = 0; k0 < FEAT; k0 += 32) {
        // stage A (x rows, fp32->bf16): 8 lanes per row, 128 B contiguous per row
#pragma unroll
        for (int i = 0; i < 4; ++i) {
            int r = lrow + 32 * i;
            int grow = bm + r;
            float4 v = make_float4(0.f, 0.f, 0.f, 0.f);
            if (grow < M) v = *(const float4*)(x + (size_t)grow * FEAT + k0 + lcol);
            uint2 pk = make_uint2(pack_bf16(v.x, v.y), pack_bf16(v.z, v.w));
            *(uint2*)(As + r * LDST + lcol) = pk;
        }
        // stage B (W1 rows, always in-bounds: 128 rows)
#pragma unroll
        for (int i = 0; i < 4; ++i) {
            int r = lrow + 32 * i;
            float4 v = *(const float4*)(W1 + (size_t)r * FEAT + k0 + lcol);
            uint2 pk = make_uint2(pack_bf16(v.x, v.y), pack_bf16(v.z, v.w));
            *(uint2*)(Bs + r * LDST + lcol) = pk;
        }
        __syncthreads();
        short8 af[4], bfr[4];
#pragma unroll
        for (int t = 0; t < 4; ++t)
            af[t] = *(const short8*)(As + (rh + t * 16 + sub) * LDST + quad * 8);
#pragma unroll
        for (int u = 0; u < 4; ++u)
            bfr[u] = *(const short8*)(Bs + (ch + u * 16 + sub) * LDST + quad * 8);
#pragma unroll
        for (int t = 0; t < 4; ++t)
#pragma unroll
            for (int u = 0; u < 4; ++u)
                acc[t][u] = __builtin_amdgcn_mfma_f32_16x16x32_bf16(af[t], bfr[u], acc[t][u], 0, 0, 0);
        __syncthreads();
    }
    // epilogue: C/D map col=lane&15, row=(lane>>4)*4+reg
    float b1v[4];
#pragma unroll
    for (int u = 0; u < 4; ++u) b1v[u] = b1[ch + u * 16 + sub];
#pragma unroll
    for (int t = 0; t < 4; ++t) {
#pragma unroll
        for (int u = 0; u < 4; ++u) {
            int col = ch + u * 16 + sub;
#pragma unroll
            for (int r2 = 0; r2 < 4; ++r2) {
                int grow = bm + rh + t * 16 + quad * 4 + r2;
                if (grow < M)
                    h[(size_t)grow * HIDDEN + col] = fmaxf(acc[t][u][r2] + b1v[u], 0.f);
            }
        }
    }
}

// ---------------- prep: bf16 pack + layer-0 dots ----------------
__global__ void k_prep(const float* __restrict__ h, unsigned* __restrict__ hbf,
                       const float* __restrict__ attl, const float* __restrict__ attr,
                       float* __restrict__ al, float* __restrict__ ar, int n) {
    int node = (blockIdx.x * blockDim.x + threadIdx.x) >> 6;
    int lane = threadIdx.x & 63;
    if (node >= n) return;
    float2 hv = ((const float2*)(h + (size_t)node * HIDDEN))[lane];
    hbf[(size_t)node * 64 + lane] = pack_bf16(hv.x, hv.y);
    float pl = hv.x * attl[2 * lane] + hv.y * attl[2 * lane + 1];
    float pr = hv.x * attr[2 * lane] + hv.y * attr[2 * lane + 1];
    for (int off = 32; off; off >>= 1) {
        pl += __shfl_down(pl, off);
        pr += __shfl_down(pr, off);
    }
    if (lane == 0) {
        al[node] = pl;
        ar[node] = pr;
    }
}

// ---------------- edge records: ep = {src, tanh(al[s]+ar[d])*norm} --------------
__global__ void k_coef(const int* __restrict__ csrc, const int* __restrict__ cdst,
                       const float* __restrict__ cnrm, const float* __restrict__ al,
                       const float* __restrict__ ar, int2* __restrict__ ep, int E) {
    int e = blockIdx.x * 256 + threadIdx.x;
    if (e < E) {
        int s = csrc[e], d = cdst[e];
        float c = tanhf(al[s] + ar[d]) * cnrm[e];
        ep[e] = make_int2(s, __float_as_int(c));
    }
}

// ---------------- aggregate: 4 rows per vmem instr (16 lanes x 16B) -------------
__global__ void k_aggregate(const unsigned* __restrict__ hbf, const float* __restrict__ raw,
                            const float* __restrict__ al, const float* __restrict__ ar,
                            const float* __restrict__ dis, const int* __restrict__ offs,
                            const int2* __restrict__ ep, float* __restrict__ hout,
                            unsigned* __restrict__ houtbf,
                            const float* __restrict__ attl_n, const float* __restrict__ attr_n,
                            float* __restrict__ al_o, float* __restrict__ ar_o, int n) {
    int node = (blockIdx.x * blockDim.x + threadIdx.x) >> 6;
    int lane = threadIdx.x & 63;
    if (node >= n) return;
    const int grp = lane >> 4;   // which of 4 rows in a group
    const int sub = lane & 15;   // feature chunk: sub*8 .. sub*8+7
    float acc[8] = {0.f, 0.f, 0.f, 0.f, 0.f, 0.f, 0.f, 0.f};
    int e0 = offs[node], e1 = offs[node + 1];
    int e = e0;
    // 8 edges per iteration: 2 x (4 rows per vmem instruction)
    for (; e + 8 <= e1; e += 8) {
        int2 pa = ep[e + grp];
        int2 pb = ep[e + 4 + grp];
        uint4 ra = *(const uint4*)(hbf + (size_t)pa.x * 64 + sub * 4);
        uint4 rb = *(const uint4*)(hbf + (size_t)pb.x * 64 + sub * 4);
        float ca = __int_as_float(pa.y), cb = __int_as_float(pb.y);
        acc[0] += ca * bf_lo(ra.x); acc[1] += ca * bf_hi(ra.x);
        acc[2] += ca * bf_lo(ra.y); acc[3] += ca * bf_hi(ra.y);
        acc[4] += ca * bf_lo(ra.z); acc[5] += ca * bf_hi(ra.z);
        acc[6] += ca * bf_lo(ra.w); acc[7] += ca * bf_hi(ra.w);
        acc[0] += cb * bf_lo(rb.x); acc[1] += cb * bf_hi(rb.x);
        acc[2] += cb * bf_lo(rb.y); acc[3] += cb * bf_hi(rb.y);
        acc[4] += cb * bf_lo(rb.z); acc[5] += cb * bf_hi(rb.z);
        acc[6] += cb * bf_lo(rb.w); acc[7] += cb * bf_hi(rb.w);
    }
    for (; e + 4 <= e1; e += 4) {
        int2 pa = ep[e + grp];
        uint4 ra = *(const uint4*)(hbf + (size_t)pa.x * 64 + sub * 4);
        float ca = __int_as_float(pa.y);
        acc[0] += ca * bf_lo(ra.x); acc[1] += ca * bf_hi(ra.x);
        acc[2] += ca * bf_lo(ra.y); acc[3] += ca * bf_hi(ra.y);
        acc[4] += ca * bf_lo(ra.z); acc[5] += ca * bf_hi(ra.z);
        acc[6] += ca * bf_lo(ra.w); acc[7] += ca * bf_hi(ra.w);
    }
    // combine the 4 row-groups; afterwards all lanes with the same `sub` agree
#pragma unroll
    for (int j = 0; j < 8; ++j) {
        acc[j] += __shfl_xor(acc[j], 16);
        acc[j] += __shfl_xor(acc[j], 32);
    }
    // scalar tail (every lane adds the same value -> replication preserved)
    for (; e < e1; ++e) {
        int2 p = ep[e];
        uint4 r = *(const uint4*)(hbf + (size_t)p.x * 64 + sub * 4);
        float c = __int_as_float(p.y);
        acc[0] += c * bf_lo(r.x); acc[1] += c * bf_hi(r.x);
        acc[2] += c * bf_lo(r.y); acc[3] += c * bf_hi(r.y);
        acc[4] += c * bf_lo(r.z); acc[5] += c * bf_hi(r.z);
        acc[6] += c * bf_lo(r.w); acc[7] += c * bf_hi(r.w);
    }
    // self loop (bf16 row, norm = dis^2)
    {
        float di = dis[node];
        float c = tanhf(al[node] + ar[node]) * di * di;
        uint4 r = *(const uint4*)(hbf + (size_t)node * 64 + sub * 4);
        acc[0] += c * bf_lo(r.x); acc[1] += c * bf_hi(r.x);
        acc[2] += c * bf_lo(r.y); acc[3] += c * bf_hi(r.y);
        acc[4] += c * bf_lo(r.z); acc[5] += c * bf_hi(r.z);
        acc[6] += c * bf_lo(r.w); acc[7] += c * bf_hi(r.w);
    }
    // + eps * raw
    float o[8];
    {
        float4 rv0 = *(const float4*)(raw + (size_t)node * HIDDEN + sub * 8);
        float4 rv1 = *(const float4*)(raw + (size_t)node * HIDDEN + sub * 8 + 4);
        o[0] = acc[0] + 0.3f * rv0.x; o[1] = acc[1] + 0.3f * rv0.y;
        o[2] = acc[2] + 0.3f * rv0.z; o[3] = acc[3] + 0.3f * rv0.w;
        o[4] = acc[4] + 0.3f * rv1.x; o[5] = acc[5] + 0.3f * rv1.y;
        o[6] = acc[6] + 0.3f * rv1.z; o[7] = acc[7] + 0.3f * rv1.w;
    }
    if (grp == 0) {
        *(float4*)(hout + (size_t)node * HIDDEN + sub * 8) = make_float4(o[0], o[1], o[2], o[3]);
        *(float4*)(hout + (size_t)node * HIDDEN + sub * 8 + 4) = make_float4(o[4], o[5], o[6], o[7]);
        if (houtbf) {
            uint4 pk = make_uint4(pack_bf16(o[0], o[1]), pack_bf16(o[2], o[3]),
                                  pack_bf16(o[4], o[5]), pack_bf16(o[6], o[7]));
            *(uint4*)(houtbf + (size_t)node * 64 + sub * 4) = pk;
        }
    }
    if (attl_n) {  // fused dots for next layer
        float4 a0 = *(const float4*)(attl_n + sub * 8);
        float4 a1 = *(const float4*)(attl_n + sub * 8 + 4);
        float4 c0 = *(const float4*)(attr_n + sub * 8);
        float4 c1 = *(const float4*)(attr_n + sub * 8 + 4);
        float pl = o[0] * a0.x + o[1] * a0.y + o[2] * a0.z + o[3] * a0.w +
                   o[4] * a1.x + o[5] * a1.y + o[6] * a1.z + o[7] * a1.w;
        float pr = o[0] * c0.x + o[1] * c0.y + o[2] * c0.z + o[3] * c0.w +
                   o[4] * c1.x + o[5] * c1.y + o[6] * c1.z + o[7] * c1.w;
        for (int off = 8; off; off >>= 1) {
            pl += __shfl_xor(pl, off);
            pr += __shfl_xor(pr, off);
        }
        if (lane == 0) {
            al_o[node] = pl;
            ar_o[node] = pr;
        }
    }
}

// ---------------- output: log_softmax(h @ W2^T + b2), 4 nodes/block ------------
__global__ void k_out(const float* __restrict__ h, const float* __restrict__ W2,
                      const float* __restrict__ b2, float* __restrict__ out, int n) {
    __shared__ float hs[4][HIDDEN];
    int wave = threadIdx.x >> 6, lane = threadIdx.x & 63;
    int node = blockIdx.x * 4 + wave;
    if (node >= n) return;
    ((float2*)hs[wave])[lane] = ((const float2*)(h + (size_t)node * HIDDEN))[lane];
    float y = -INFINITY;
    if (lane < NCLASS) {
        y = b2[lane];
        const float* w = W2 + (size_t)lane * HIDDEN;
#pragma unroll 8
        for (int k = 0; k < HIDDEN; ++k) y += w[k] * hs[wave][k];
    }
    float m = y;
    for (int off = 32; off; off >>= 1) m = fmaxf(m, __shfl_xor(m, off));
    float ex = (lane < NCLASS) ? expf(y - m) : 0.f;
    float ssum = ex;
    for (int off = 32; off; off >>= 1) ssum += __shfl_xor(ssum, off);
    float lse = m + logf(ssum);
    if (lane < NCLASS) out[(size_t)node * NCLASS + lane] = y - lse;
}

extern "C" void kernel_launch(void* const* d_in, const int* in_sizes, int n_in,
                              void* d_out, int out_size, void* d_ws, size_t ws_size,
                              hipStream_t stream) {
    const float* x    = (const float*)d_in[0];
    const int*   ei   = (const int*)d_in[1];
    const float* W1   = (const float*)d_in[2];
    const float* b1   = (const float*)d_in[3];
    const float* W2   = (const float*)d_in[4];
    const float* b2   = (const float*)d_in[5];
    const float* attl = (const float*)d_in[6];
    const float* attr = (const float*)d_in[7];
    const int N = in_sizes[0] / FEAT;
    const int E = in_sizes[1] / 2;
    float* out = (float*)d_out;

    char* p = (char*)d_ws;
    auto take = [&](size_t bytes) {
        void* q = (void*)p;
        p += (bytes + 255) & ~(size_t)255;
        return q;
    };
    float*    h0   = (float*)take((size_t)N * HIDDEN * 4);  // = raw, never overwritten
    float*    h1   = (float*)take((size_t)N * HIDDEN * 4);
    float*    h2   = (float*)take((size_t)N * HIDDEN * 4);
    unsigned* hb0  = (unsigned*)take((size_t)N * 64 * 4);
    unsigned* hb1  = (unsigned*)take((size_t)N * 64 * 4);
    int*      deg  = (int*)take((size_t)N * 4);
    float*    dis  = (float*)take((size_t)N * 4);
    int*      offs = (int*)take((size_t)(N + 1) * 4);
    int*      cur  = (int*)take((size_t)N * 4);
    int*      csrc = (int*)take((size_t)E * 4);
    int*      cdst = (int*)take((size_t)E * 4);
    float*    cnrm = (float*)take((size_t)E * 4);
    int2*     ep   = (int2*)take((size_t)E * 8);
    float*    al   = (float*)take((size_t)N * 4);
    float*    ar   = (float*)take((size_t)N * 4);
    int*      part = (int*)take(1024);

    hipMemsetAsync(deg, 0, (size_t)N * 4, stream);
    hipMemsetAsync(cur, 0, (size_t)N * 4, stream);

    const int ebl = (E + 255) / 256;
    const int nbl = (N + 255) / 256;

    k_degree<<<ebl, 256, 0, stream>>>(ei, E, deg);
    k_dis<<<nbl, 256, 0, stream>>>(deg, dis, N);
    k_scan1<<<nbl, 256, 0, stream>>>(deg, offs, part, N);
    k_scan2<<<1, 256, 0, stream>>>(part, nbl);
    k_scan3<<<nbl, 256, 0, stream>>>(offs, part, N, E);
    k_csr_fill<<<ebl, 256, 0, stream>>>(ei, E, offs, cur, dis, csrc, cdst, cnrm);

    k_gemm1<<<(N + 127) / 128, 256, 0, stream>>>(x, W1, b1, h0, N);
    k_prep<<<(N + 3) / 4, 256, 0, stream>>>(h0, hb0, attl, attr, al, ar, N);

    float*    fout[4] = {h1, h2, h1, h2};
    unsigned* hbin = hb0, *hbout = hb1;
    const float* fin = h0;
    for (int l = 0; l < 4; ++l) {
        k_coef<<<ebl, 256, 0, stream>>>(csrc, cdst, cnrm, al, ar, ep, E);
        const float* attl_n = (l < 3) ? (attl + (l + 1) * HIDDEN) : nullptr;
        const float* attr_n = (l < 3) ? (attr + (l + 1) * HIDDEN) : nullptr;
        unsigned* hbo = (l < 3) ? hbout : nullptr;
        k_aggregate<<<(N + 3) / 4, 256, 0, stream>>>(hbin, h0, al, ar, dis, offs, ep,
                                                     fout[l], hbo, attl_n, attr_n, al, ar, N);
        unsigned* tb = hbin; hbin = hbout; hbout = tb;
        (void)fin;
    }

    k_out<<<(N + 3) / 4, 256, 0, stream>>>(h2, W2, b2, out, N);
}

// Round 4
// 738.546 us; speedup vs baseline: 1.7803x; 1.1152x over previous
//
#include <hip/hip_runtime.h>
#include <cmath>

// FAGCN: N=50000, E=1.6M, FEAT=512, HIDDEN=128, CLASS=40, 4 layers, eps=0.3
// R4: k_out rewritten as LDS-broadcast GEMM (W2 staged once per block, 1 node/thread,
// 40 fp32 accumulators, k-tiled float4). Rest unchanged from R3.

#define HIDDEN 128
#define FEAT 512
#define NCLASS 40
#define LDST 40  // LDS row stride in ushorts (80 B, 16B-aligned, conflict-reducing pad)

typedef __attribute__((ext_vector_type(8))) short short8;
typedef __attribute__((ext_vector_type(4))) float f32x4;

__device__ __forceinline__ float bf_lo(unsigned u) { return __uint_as_float(u << 16); }
__device__ __forceinline__ float bf_hi(unsigned u) { return __uint_as_float(u & 0xffff0000u); }
__device__ __forceinline__ unsigned pack_bf16(float x, float y) {
    unsigned ux = __float_as_uint(x);
    unsigned uy = __float_as_uint(y);
    unsigned lx = (ux + 0x7fffu + ((ux >> 16) & 1u)) >> 16;
    unsigned hy = (uy + 0x7fffu + ((uy >> 16) & 1u)) & 0xffff0000u;
    return hy | lx;
}

// ---------------- degree / dis ----------------
__global__ void k_degree(const int* __restrict__ ei, int E, int* __restrict__ deg) {
    int e = blockIdx.x * 256 + threadIdx.x;
    if (e < E) atomicAdd(&deg[ei[E + e]], 1);
}

__global__ void k_dis(const int* __restrict__ deg, float* __restrict__ dis, int n) {
    int i = blockIdx.x * 256 + threadIdx.x;
    if (i < n) dis[i] = rsqrtf((float)(deg[i] + 1));
}

// ---------------- exclusive scan ----------------
__global__ void k_scan1(const int* __restrict__ deg, int* __restrict__ offs,
                        int* __restrict__ part, int n) {
    __shared__ int s[256];
    int tid = threadIdx.x;
    int gid = blockIdx.x * 256 + tid;
    int v = (gid < n) ? deg[gid] : 0;
    s[tid] = v;
    __syncthreads();
    for (int off = 1; off < 256; off <<= 1) {
        int t = (tid >= off) ? s[tid - off] : 0;
        __syncthreads();
        s[tid] += t;
        __syncthreads();
    }
    if (gid < n) offs[gid] = s[tid] - v;
    if (tid == 255) part[blockIdx.x] = s[255];
}

__global__ void k_scan2(int* __restrict__ part, int nb) {
    __shared__ int s[256];
    int tid = threadIdx.x;
    int v = (tid < nb) ? part[tid] : 0;
    s[tid] = v;
    __syncthreads();
    for (int off = 1; off < 256; off <<= 1) {
        int t = (tid >= off) ? s[tid - off] : 0;
        __syncthreads();
        s[tid] += t;
        __syncthreads();
    }
    if (tid < nb) part[tid] = s[tid] - v;
}

__global__ void k_scan3(int* __restrict__ offs, const int* __restrict__ part, int n, int E) {
    int gid = blockIdx.x * 256 + threadIdx.x;
    if (gid < n) offs[gid] += part[blockIdx.x];
    if (gid == 0) offs[n] = E;
}

// ---------------- CSR fill ----------------
__global__ void k_csr_fill(const int* __restrict__ ei, int E,
                           const int* __restrict__ offs, int* __restrict__ cur,
                           const float* __restrict__ dis,
                           int* __restrict__ csrc, int* __restrict__ cdst,
                           float* __restrict__ cnrm) {
    int e = blockIdx.x * 256 + threadIdx.x;
    if (e >= E) return;
    int src = ei[e];
    int dst = ei[E + e];
    int pos = offs[dst] + atomicAdd(&cur[dst], 1);
    csrc[pos] = src;
    cdst[pos] = dst;
    cnrm[pos] = dis[src] * dis[dst];
}

// ---------------- GEMM1: h = relu(x @ W1^T + b1), MFMA bf16 -------------------
__global__ __launch_bounds__(256) void k_gemm1(const float* __restrict__ x,
                                               const float* __restrict__ W1,
                                               const float* __restrict__ b1,
                                               float* __restrict__ h, int M) {
    __shared__ ushort As[128 * LDST];
    __shared__ ushort Bs[128 * LDST];
    const int tid = threadIdx.x;
    const int bm = blockIdx.x * 128;
    const int wave = tid >> 6, lane = tid & 63;
    const int rh = (wave >> 1) * 64;
    const int ch = (wave & 1) * 64;
    const int sub = lane & 15, quad = lane >> 4;
    const int lrow = tid >> 3;
    const int lcol = (tid & 7) * 4;
    f32x4 acc[4][4] = {};
    for (int k0 = 0; k0 < FEAT; k0 += 32) {
#pragma unroll
        for (int i = 0; i < 4; ++i) {
            int r = lrow + 32 * i;
            int grow = bm + r;
            float4 v = make_float4(0.f, 0.f, 0.f, 0.f);
            if (grow < M) v = *(const float4*)(x + (size_t)grow * FEAT + k0 + lcol);
            uint2 pk = make_uint2(pack_bf16(v.x, v.y), pack_bf16(v.z, v.w));
            *(uint2*)(As + r * LDST + lcol) = pk;
        }
#pragma unroll
        for (int i = 0; i < 4; ++i) {
            int r = lrow + 32 * i;
            float4 v = *(const float4*)(W1 + (size_t)r * FEAT + k0 + lcol);
            uint2 pk = make_uint2(pack_bf16(v.x, v.y), pack_bf16(v.z, v.w));
            *(uint2*)(Bs + r * LDST + lcol) = pk;
        }
        __syncthreads();
        short8 af[4], bfr[4];
#pragma unroll
        for (int t = 0; t < 4; ++t)
            af[t] = *(const short8*)(As + (rh + t * 16 + sub) * LDST + quad * 8);
#pragma unroll
        for (int u = 0; u < 4; ++u)
            bfr[u] = *(const short8*)(Bs + (ch + u * 16 + sub) * LDST + quad * 8);
#pragma unroll
        for (int t = 0; t < 4; ++t)
#pragma unroll
            for (int u = 0; u < 4; ++u)
                acc[t][u] = __builtin_amdgcn_mfma_f32_16x16x32_bf16(af[t], bfr[u], acc[t][u], 0, 0, 0);
        __syncthreads();
    }
    float b1v[4];
#pragma unroll
    for (int u = 0; u < 4; ++u) b1v[u] = b1[ch + u * 16 + sub];
#pragma unroll
    for (int t = 0; t < 4; ++t) {
#pragma unroll
        for (int u = 0; u < 4; ++u) {
            int col = ch + u * 16 + sub;
#pragma unroll
            for (int r2 = 0; r2 < 4; ++r2) {
                int grow = bm + rh + t * 16 + quad * 4 + r2;
                if (grow < M)
                    h[(size_t)grow * HIDDEN + col] = fmaxf(acc[t][u][r2] + b1v[u], 0.f);
            }
        }
    }
}

// ---------------- prep: bf16 pack + layer-0 dots ----------------
__global__ void k_prep(const float* __restrict__ h, unsigned* __restrict__ hbf,
                       const float* __restrict__ attl, const float* __restrict__ attr,
                       float* __restrict__ al, float* __restrict__ ar, int n) {
    int node = (blockIdx.x * blockDim.x + threadIdx.x) >> 6;
    int lane = threadIdx.x & 63;
    if (node >= n) return;
    float2 hv = ((const float2*)(h + (size_t)node * HIDDEN))[lane];
    hbf[(size_t)node * 64 + lane] = pack_bf16(hv.x, hv.y);
    float pl = hv.x * attl[2 * lane] + hv.y * attl[2 * lane + 1];
    float pr = hv.x * attr[2 * lane] + hv.y * attr[2 * lane + 1];
    for (int off = 32; off; off >>= 1) {
        pl += __shfl_down(pl, off);
        pr += __shfl_down(pr, off);
    }
    if (lane == 0) {
        al[node] = pl;
        ar[node] = pr;
    }
}

// ---------------- edge records: ep = {src, tanh(al[s]+ar[d])*norm} --------------
__global__ void k_coef(const int* __restrict__ csrc, const int* __restrict__ cdst,
                       const float* __restrict__ cnrm, const float* __restrict__ al,
                       const float* __restrict__ ar, int2* __restrict__ ep, int E) {
    int e = blockIdx.x * 256 + threadIdx.x;
    if (e < E) {
        int s = csrc[e], d = cdst[e];
        float c = tanhf(al[s] + ar[d]) * cnrm[e];
        ep[e] = make_int2(s, __float_as_int(c));
    }
}

// ---------------- aggregate: 4 rows per vmem instr (16 lanes x 16B) -------------
__global__ void k_aggregate(const unsigned* __restrict__ hbf, const float* __restrict__ raw,
                            const float* __restrict__ al, const float* __restrict__ ar,
                            const float* __restrict__ dis, const int* __restrict__ offs,
                            const int2* __restrict__ ep, float* __restrict__ hout,
                            unsigned* __restrict__ houtbf,
                            const float* __restrict__ attl_n, const float* __restrict__ attr_n,
                            float* __restrict__ al_o, float* __restrict__ ar_o, int n) {
    int node = (blockIdx.x * blockDim.x + threadIdx.x) >> 6;
    int lane = threadIdx.x & 63;
    if (node >= n) return;
    const int grp = lane >> 4;
    const int sub = lane & 15;
    float acc[8] = {0.f, 0.f, 0.f, 0.f, 0.f, 0.f, 0.f, 0.f};
    int e0 = offs[node], e1 = offs[node + 1];
    int e = e0;
    for (; e + 8 <= e1; e += 8) {
        int2 pa = ep[e + grp];
        int2 pb = ep[e + 4 + grp];
        uint4 ra = *(const uint4*)(hbf + (size_t)pa.x * 64 + sub * 4);
        uint4 rb = *(const uint4*)(hbf + (size_t)pb.x * 64 + sub * 4);
        float ca = __int_as_float(pa.y), cb = __int_as_float(pb.y);
        acc[0] += ca * bf_lo(ra.x); acc[1] += ca * bf_hi(ra.x);
        acc[2] += ca * bf_lo(ra.y); acc[3] += ca * bf_hi(ra.y);
        acc[4] += ca * bf_lo(ra.z); acc[5] += ca * bf_hi(ra.z);
        acc[6] += ca * bf_lo(ra.w); acc[7] += ca * bf_hi(ra.w);
        acc[0] += cb * bf_lo(rb.x); acc[1] += cb * bf_hi(rb.x);
        acc[2] += cb * bf_lo(rb.y); acc[3] += cb * bf_hi(rb.y);
        acc[4] += cb * bf_lo(rb.z); acc[5] += cb * bf_hi(rb.z);
        acc[6] += cb * bf_lo(rb.w); acc[7] += cb * bf_hi(rb.w);
    }
    for (; e + 4 <= e1; e += 4) {
        int2 pa = ep[e + grp];
        uint4 ra = *(const uint4*)(hbf + (size_t)pa.x * 64 + sub * 4);
        float ca = __int_as_float(pa.y);
        acc[0] += ca * bf_lo(ra.x); acc[1] += ca * bf_hi(ra.x);
        acc[2] += ca * bf_lo(ra.y); acc[3] += ca * bf_hi(ra.y);
        acc[4] += ca * bf_lo(ra.z); acc[5] += ca * bf_hi(ra.z);
        acc[6] += ca * bf_lo(ra.w); acc[7] += ca * bf_hi(ra.w);
    }
#pragma unroll
    for (int j = 0; j < 8; ++j) {
        acc[j] += __shfl_xor(acc[j], 16);
        acc[j] += __shfl_xor(acc[j], 32);
    }
    for (; e < e1; ++e) {
        int2 p = ep[e];
        uint4 r = *(const uint4*)(hbf + (size_t)p.x * 64 + sub * 4);
        float c = __int_as_float(p.y);
        acc[0] += c * bf_lo(r.x); acc[1] += c * bf_hi(r.x);
        acc[2] += c * bf_lo(r.y); acc[3] += c * bf_hi(r.y);
        acc[4] += c * bf_lo(r.z); acc[5] += c * bf_hi(r.z);
        acc[6] += c * bf_lo(r.w); acc[7] += c * bf_hi(r.w);
    }
    {
        float di = dis[node];
        float c = tanhf(al[node] + ar[node]) * di * di;
        uint4 r = *(const uint4*)(hbf + (size_t)node * 64 + sub * 4);
        acc[0] += c * bf_lo(r.x); acc[1] += c * bf_hi(r.x);
        acc[2] += c * bf_lo(r.y); acc[3] += c * bf_hi(r.y);
        acc[4] += c * bf_lo(r.z); acc[5] += c * bf_hi(r.z);
        acc[6] += c * bf_lo(r.w); acc[7] += c * bf_hi(r.w);
    }
    float o[8];
    {
        float4 rv0 = *(const float4*)(raw + (size_t)node * HIDDEN + sub * 8);
        float4 rv1 = *(const float4*)(raw + (size_t)node * HIDDEN + sub * 8 + 4);
        o[0] = acc[0] + 0.3f * rv0.x; o[1] = acc[1] + 0.3f * rv0.y;
        o[2] = acc[2] + 0.3f * rv0.z; o[3] = acc[3] + 0.3f * rv0.w;
        o[4] = acc[4] + 0.3f * rv1.x; o[5] = acc[5] + 0.3f * rv1.y;
        o[6] = acc[6] + 0.3f * rv1.z; o[7] = acc[7] + 0.3f * rv1.w;
    }
    if (grp == 0) {
        *(float4*)(hout + (size_t)node * HIDDEN + sub * 8) = make_float4(o[0], o[1], o[2], o[3]);
        *(float4*)(hout + (size_t)node * HIDDEN + sub * 8 + 4) = make_float4(o[4], o[5], o[6], o[7]);
        if (houtbf) {
            uint4 pk = make_uint4(pack_bf16(o[0], o[1]), pack_bf16(o[2], o[3]),
                                  pack_bf16(o[4], o[5]), pack_bf16(o[6], o[7]));
            *(uint4*)(houtbf + (size_t)node * 64 + sub * 4) = pk;
        }
    }
    if (attl_n) {
        float4 a0 = *(const float4*)(attl_n + sub * 8);
        float4 a1 = *(const float4*)(attl_n + sub * 8 + 4);
        float4 c0 = *(const float4*)(attr_n + sub * 8);
        float4 c1 = *(const float4*)(attr_n + sub * 8 + 4);
        float pl = o[0] * a0.x + o[1] * a0.y + o[2] * a0.z + o[3] * a0.w +
                   o[4] * a1.x + o[5] * a1.y + o[6] * a1.z + o[7] * a1.w;
        float pr = o[0] * c0.x + o[1] * c0.y + o[2] * c0.z + o[3] * c0.w +
                   o[4] * c1.x + o[5] * c1.y + o[6] * c1.z + o[7] * c1.w;
        for (int off = 8; off; off >>= 1) {
            pl += __shfl_xor(pl, off);
            pr += __shfl_xor(pr, off);
        }
        if (lane == 0) {
            al_o[node] = pl;
            ar_o[node] = pr;
        }
    }
}

// ---------------- output: log_softmax(h @ W2^T + b2) ---------------------------
// LDS-broadcast GEMM: W2 (20KB) staged once per block; 1 node/thread, 40 fp32 acc.
__global__ __launch_bounds__(256) void k_out(const float* __restrict__ h,
                                             const float* __restrict__ W2,
                                             const float* __restrict__ b2,
                                             float* __restrict__ out, int n) {
    __shared__ float ws[NCLASS * HIDDEN];  // broadcast reads -> no conflicts
    __shared__ float bs[NCLASS];
    const int tid = threadIdx.x;
    // stage W2: 5120 floats = 1280 float4, 5 per thread
    for (int i = tid; i < NCLASS * HIDDEN / 4; i += 256)
        ((float4*)ws)[i] = ((const float4*)W2)[i];
    if (tid < NCLASS) bs[tid] = b2[tid];
    __syncthreads();
    int node = blockIdx.x * 256 + tid;
    if (node >= n) return;
    const float* hr = h + (size_t)node * HIDDEN;
    float acc[NCLASS];
#pragma unroll
    for (int c = 0; c < NCLASS; ++c) acc[c] = bs[c];
#pragma unroll
    for (int k0 = 0; k0 < HIDDEN; k0 += 16) {
        float4 h0 = *(const float4*)(hr + k0);
        float4 h1 = *(const float4*)(hr + k0 + 4);
        float4 h2 = *(const float4*)(hr + k0 + 8);
        float4 h3 = *(const float4*)(hr + k0 + 12);
#pragma unroll
        for (int c = 0; c < NCLASS; ++c) {
            const float* w = ws + c * HIDDEN + k0;
            float4 w0 = *(const float4*)(w);
            float4 w1 = *(const float4*)(w + 4);
            float4 w2v = *(const float4*)(w + 8);
            float4 w3 = *(const float4*)(w + 12);
            acc[c] += h0.x * w0.x + h0.y * w0.y + h0.z * w0.z + h0.w * w0.w +
                      h1.x * w1.x + h1.y * w1.y + h1.z * w1.z + h1.w * w1.w +
                      h2.x * w2v.x + h2.y * w2v.y + h2.z * w2v.z + h2.w * w2v.w +
                      h3.x * w3.x + h3.y * w3.y + h3.z * w3.z + h3.w * w3.w;
        }
    }
    float m = -INFINITY;
#pragma unroll
    for (int c = 0; c < NCLASS; ++c) m = fmaxf(m, acc[c]);
    float ssum = 0.f;
#pragma unroll
    for (int c = 0; c < NCLASS; ++c) ssum += expf(acc[c] - m);
    float lse = m + logf(ssum);
    float* orow = out + (size_t)node * NCLASS;
#pragma unroll
    for (int c = 0; c < NCLASS; ++c) orow[c] = acc[c] - lse;
}

extern "C" void kernel_launch(void* const* d_in, const int* in_sizes, int n_in,
                              void* d_out, int out_size, void* d_ws, size_t ws_size,
                              hipStream_t stream) {
    const float* x    = (const float*)d_in[0];
    const int*   ei   = (const int*)d_in[1];
    const float* W1   = (const float*)d_in[2];
    const float* b1   = (const float*)d_in[3];
    const float* W2   = (const float*)d_in[4];
    const float* b2   = (const float*)d_in[5];
    const float* attl = (const float*)d_in[6];
    const float* attr = (const float*)d_in[7];
    const int N = in_sizes[0] / FEAT;
    const int E = in_sizes[1] / 2;
    float* out = (float*)d_out;

    char* p = (char*)d_ws;
    auto take = [&](size_t bytes) {
        void* q = (void*)p;
        p += (bytes + 255) & ~(size_t)255;
        return q;
    };
    float*    h0   = (float*)take((size_t)N * HIDDEN * 4);  // = raw, never overwritten
    float*    h1   = (float*)take((size_t)N * HIDDEN * 4);
    float*    h2   = (float*)take((size_t)N * HIDDEN * 4);
    unsigned* hb0  = (unsigned*)take((size_t)N * 64 * 4);
    unsigned* hb1  = (unsigned*)take((size_t)N * 64 * 4);
    int*      deg  = (int*)take((size_t)N * 4);
    float*    dis  = (float*)take((size_t)N * 4);
    int*      offs = (int*)take((size_t)(N + 1) * 4);
    int*      cur  = (int*)take((size_t)N * 4);
    int*      csrc = (int*)take((size_t)E * 4);
    int*      cdst = (int*)take((size_t)E * 4);
    float*    cnrm = (float*)take((size_t)E * 4);
    int2*     ep   = (int2*)take((size_t)E * 8);
    float*    al   = (float*)take((size_t)N * 4);
    float*    ar   = (float*)take((size_t)N * 4);
    int*      part = (int*)take(1024);

    hipMemsetAsync(deg, 0, (size_t)N * 4, stream);
    hipMemsetAsync(cur, 0, (size_t)N * 4, stream);

    const int ebl = (E + 255) / 256;
    const int nbl = (N + 255) / 256;

    k_degree<<<ebl, 256, 0, stream>>>(ei, E, deg);
    k_dis<<<nbl, 256, 0, stream>>>(deg, dis, N);
    k_scan1<<<nbl, 256, 0, stream>>>(deg, offs, part, N);
    k_scan2<<<1, 256, 0, stream>>>(part, nbl);
    k_scan3<<<nbl, 256, 0, stream>>>(offs, part, N, E);
    k_csr_fill<<<ebl, 256, 0, stream>>>(ei, E, offs, cur, dis, csrc, cdst, cnrm);

    k_gemm1<<<(N + 127) / 128, 256, 0, stream>>>(x, W1, b1, h0, N);
    k_prep<<<(N + 3) / 4, 256, 0, stream>>>(h0, hb0, attl, attr, al, ar, N);

    float*    fout[4] = {h1, h2, h1, h2};
    unsigned* hbin = hb0, *hbout = hb1;
    for (int l = 0; l < 4; ++l) {
        k_coef<<<ebl, 256, 0, stream>>>(csrc, cdst, cnrm, al, ar, ep, E);
        const float* attl_n = (l < 3) ? (attl + (l + 1) * HIDDEN) : nullptr;
        const float* attr_n = (l < 3) ? (attr + (l + 1) * HIDDEN) : nullptr;
        unsigned* hbo = (l < 3) ? hbout : nullptr;
        k_aggregate<<<(N + 3) / 4, 256, 0, stream>>>(hbin, h0, al, ar, dis, offs, ep,
                                                     fout[l], hbo, attl_n, attr_n, al, ar, N);
        unsigned* tb = hbin; hbin = hbout; hbout = tb;
    }

    k_out<<<(N + 255) / 256, 256, 0, stream>>>(h2, W2, b2, out, N);
}

// Round 5
// 701.196 us; speedup vs baseline: 1.8752x; 1.0533x over previous
//
#include <hip/hip_runtime.h>
#include <cmath>

// FAGCN: N=50000, E=1.6M, FEAT=512, HIDDEN=128, CLASS=40, 4 layers, eps=0.3
// R5: csr_fill scatter reduced to ONE 4B store/edge (cdst/cnrm eliminated);
// k_coef folded into k_aggregate (inline tanh, {al,dis} float2 broadcast gather,
// al/ar double-buffered across layers). k_out/gemm1 unchanged from R4.

#define HIDDEN 128
#define FEAT 512
#define NCLASS 40
#define LDST 40  // LDS row stride in ushorts (80 B)

typedef __attribute__((ext_vector_type(8))) short short8;
typedef __attribute__((ext_vector_type(4))) float f32x4;

__device__ __forceinline__ float bf_lo(unsigned u) { return __uint_as_float(u << 16); }
__device__ __forceinline__ float bf_hi(unsigned u) { return __uint_as_float(u & 0xffff0000u); }
__device__ __forceinline__ unsigned pack_bf16(float x, float y) {
    unsigned ux = __float_as_uint(x);
    unsigned uy = __float_as_uint(y);
    unsigned lx = (ux + 0x7fffu + ((ux >> 16) & 1u)) >> 16;
    unsigned hy = (uy + 0x7fffu + ((uy >> 16) & 1u)) & 0xffff0000u;
    return hy | lx;
}
__device__ __forceinline__ float fast_tanh(float x) {
    x = fminf(fmaxf(x, -15.f), 15.f);           // saturate: tanh(+-15) == +-1 in fp32
    float e = __expf(2.f * x);
    return (e - 1.f) / (e + 1.f);
}

// ---------------- degree / dis ----------------
__global__ void k_degree(const int* __restrict__ ei, int E, int* __restrict__ deg) {
    int e = blockIdx.x * 256 + threadIdx.x;
    if (e < E) atomicAdd(&deg[ei[E + e]], 1);
}

__global__ void k_dis(const int* __restrict__ deg, float* __restrict__ dis, int n) {
    int i = blockIdx.x * 256 + threadIdx.x;
    if (i < n) dis[i] = rsqrtf((float)(deg[i] + 1));
}

// ---------------- exclusive scan ----------------
__global__ void k_scan1(const int* __restrict__ deg, int* __restrict__ offs,
                        int* __restrict__ part, int n) {
    __shared__ int s[256];
    int tid = threadIdx.x;
    int gid = blockIdx.x * 256 + tid;
    int v = (gid < n) ? deg[gid] : 0;
    s[tid] = v;
    __syncthreads();
    for (int off = 1; off < 256; off <<= 1) {
        int t = (tid >= off) ? s[tid - off] : 0;
        __syncthreads();
        s[tid] += t;
        __syncthreads();
    }
    if (gid < n) offs[gid] = s[tid] - v;
    if (tid == 255) part[blockIdx.x] = s[255];
}

__global__ void k_scan2(int* __restrict__ part, int nb) {
    __shared__ int s[256];
    int tid = threadIdx.x;
    int v = (tid < nb) ? part[tid] : 0;
    s[tid] = v;
    __syncthreads();
    for (int off = 1; off < 256; off <<= 1) {
        int t = (tid >= off) ? s[tid - off] : 0;
        __syncthreads();
        s[tid] += t;
        __syncthreads();
    }
    if (tid < nb) part[tid] = s[tid] - v;
}

__global__ void k_scan3(int* __restrict__ offs, const int* __restrict__ part, int n, int E) {
    int gid = blockIdx.x * 256 + threadIdx.x;
    if (gid < n) offs[gid] += part[blockIdx.x];
    if (gid == 0) offs[n] = E;
}

// ---------------- CSR fill: single 4B scatter per edge ----------------
// cur[] starts as a copy of offs[]; atomicAdd returns the slot directly.
__global__ void k_csr_fill(const int* __restrict__ ei, int E, int* __restrict__ cur,
                           int* __restrict__ csrc) {
    int e = blockIdx.x * 256 + threadIdx.x;
    if (e >= E) return;
    int src = ei[e];
    int dst = ei[E + e];
    int pos = atomicAdd(&cur[dst], 1);
    csrc[pos] = src;
}

// ---------------- GEMM1: h = relu(x @ W1^T + b1), MFMA bf16 -------------------
__global__ __launch_bounds__(256) void k_gemm1(const float* __restrict__ x,
                                               const float* __restrict__ W1,
                                               const float* __restrict__ b1,
                                               float* __restrict__ h, int M) {
    __shared__ ushort As[128 * LDST];
    __shared__ ushort Bs[128 * LDST];
    const int tid = threadIdx.x;
    const int bm = blockIdx.x * 128;
    const int wave = tid >> 6, lane = tid & 63;
    const int rh = (wave >> 1) * 64;
    const int ch = (wave & 1) * 64;
    const int sub = lane & 15, quad = lane >> 4;
    const int lrow = tid >> 3;
    const int lcol = (tid & 7) * 4;
    f32x4 acc[4][4] = {};
    for (int k0 = 0; k0 < FEAT; k0 += 32) {
#pragma unroll
        for (int i = 0; i < 4; ++i) {
            int r = lrow + 32 * i;
            int grow = bm + r;
            float4 v = make_float4(0.f, 0.f, 0.f, 0.f);
            if (grow < M) v = *(const float4*)(x + (size_t)grow * FEAT + k0 + lcol);
            uint2 pk = make_uint2(pack_bf16(v.x, v.y), pack_bf16(v.z, v.w));
            *(uint2*)(As + r * LDST + lcol) = pk;
        }
#pragma unroll
        for (int i = 0; i < 4; ++i) {
            int r = lrow + 32 * i;
            float4 v = *(const float4*)(W1 + (size_t)r * FEAT + k0 + lcol);
            uint2 pk = make_uint2(pack_bf16(v.x, v.y), pack_bf16(v.z, v.w));
            *(uint2*)(Bs + r * LDST + lcol) = pk;
        }
        __syncthreads();
        short8 af[4], bfr[4];
#pragma unroll
        for (int t = 0; t < 4; ++t)
            af[t] = *(const short8*)(As + (rh + t * 16 + sub) * LDST + quad * 8);
#pragma unroll
        for (int u = 0; u < 4; ++u)
            bfr[u] = *(const short8*)(Bs + (ch + u * 16 + sub) * LDST + quad * 8);
#pragma unroll
        for (int t = 0; t < 4; ++t)
#pragma unroll
            for (int u = 0; u < 4; ++u)
                acc[t][u] = __builtin_amdgcn_mfma_f32_16x16x32_bf16(af[t], bfr[u], acc[t][u], 0, 0, 0);
        __syncthreads();
    }
    float b1v[4];
#pragma unroll
    for (int u = 0; u < 4; ++u) b1v[u] = b1[ch + u * 16 + sub];
#pragma unroll
    for (int t = 0; t < 4; ++t) {
#pragma unroll
        for (int u = 0; u < 4; ++u) {
            int col = ch + u * 16 + sub;
#pragma unroll
            for (int r2 = 0; r2 < 4; ++r2) {
                int grow = bm + rh + t * 16 + quad * 4 + r2;
                if (grow < M)
                    h[(size_t)grow * HIDDEN + col] = fmaxf(acc[t][u][r2] + b1v[u], 0.f);
            }
        }
    }
}

// ---------------- prep: bf16 pack + layer-0 dots -> {al,dis}, ar ----------------
__global__ void k_prep(const float* __restrict__ h, unsigned* __restrict__ hbf,
                       const float* __restrict__ attl, const float* __restrict__ attr,
                       const float* __restrict__ dis, float2* __restrict__ al2,
                       float* __restrict__ ar, int n) {
    int node = (blockIdx.x * blockDim.x + threadIdx.x) >> 6;
    int lane = threadIdx.x & 63;
    if (node >= n) return;
    float2 hv = ((const float2*)(h + (size_t)node * HIDDEN))[lane];
    hbf[(size_t)node * 64 + lane] = pack_bf16(hv.x, hv.y);
    float pl = hv.x * attl[2 * lane] + hv.y * attl[2 * lane + 1];
    float pr = hv.x * attr[2 * lane] + hv.y * attr[2 * lane + 1];
    for (int off = 32; off; off >>= 1) {
        pl += __shfl_down(pl, off);
        pr += __shfl_down(pr, off);
    }
    if (lane == 0) {
        al2[node] = make_float2(pl, dis[node]);
        ar[node] = pr;
    }
}

// ---------------- aggregate with inline coef ----------------
// one wave per node; 16-lane groups each own one edge; coef computed in-wave.
__global__ void k_aggregate(const unsigned* __restrict__ hbf, const float* __restrict__ raw,
                            const float2* __restrict__ al2, const float* __restrict__ ar,
                            const int* __restrict__ offs, const int* __restrict__ csrc,
                            float* __restrict__ hout, unsigned* __restrict__ houtbf,
                            const float* __restrict__ attl_n, const float* __restrict__ attr_n,
                            float2* __restrict__ al2_o, float* __restrict__ ar_o, int n) {
    int node = (blockIdx.x * blockDim.x + threadIdx.x) >> 6;
    int lane = threadIdx.x & 63;
    if (node >= n) return;
    const int grp = lane >> 4;
    const int sub = lane & 15;
    const float arn = ar[node];
    const float2 selfld = al2[node];      // {al[node], dis[node]}
    const float disn = selfld.y;
    float acc[8] = {0.f, 0.f, 0.f, 0.f, 0.f, 0.f, 0.f, 0.f};
    int e0 = offs[node], e1 = offs[node + 1];
    int e = e0;
    for (; e + 8 <= e1; e += 8) {
        int sa = csrc[e + grp];
        int sb = csrc[e + 4 + grp];
        float2 la = al2[sa];
        float2 lb = al2[sb];
        uint4 ra = *(const uint4*)(hbf + (size_t)sa * 64 + sub * 4);
        uint4 rb = *(const uint4*)(hbf + (size_t)sb * 64 + sub * 4);
        float ca = fast_tanh(la.x + arn) * la.y * disn;
        float cb = fast_tanh(lb.x + arn) * lb.y * disn;
        acc[0] += ca * bf_lo(ra.x); acc[1] += ca * bf_hi(ra.x);
        acc[2] += ca * bf_lo(ra.y); acc[3] += ca * bf_hi(ra.y);
        acc[4] += ca * bf_lo(ra.z); acc[5] += ca * bf_hi(ra.z);
        acc[6] += ca * bf_lo(ra.w); acc[7] += ca * bf_hi(ra.w);
        acc[0] += cb * bf_lo(rb.x); acc[1] += cb * bf_hi(rb.x);
        acc[2] += cb * bf_lo(rb.y); acc[3] += cb * bf_hi(rb.y);
        acc[4] += cb * bf_lo(rb.z); acc[5] += cb * bf_hi(rb.z);
        acc[6] += cb * bf_lo(rb.w); acc[7] += cb * bf_hi(rb.w);
    }
    for (; e + 4 <= e1; e += 4) {
        int sa = csrc[e + grp];
        float2 la = al2[sa];
        uint4 ra = *(const uint4*)(hbf + (size_t)sa * 64 + sub * 4);
        float ca = fast_tanh(la.x + arn) * la.y * disn;
        acc[0] += ca * bf_lo(ra.x); acc[1] += ca * bf_hi(ra.x);
        acc[2] += ca * bf_lo(ra.y); acc[3] += ca * bf_hi(ra.y);
        acc[4] += ca * bf_lo(ra.z); acc[5] += ca * bf_hi(ra.z);
        acc[6] += ca * bf_lo(ra.w); acc[7] += ca * bf_hi(ra.w);
    }
#pragma unroll
    for (int j = 0; j < 8; ++j) {
        acc[j] += __shfl_xor(acc[j], 16);
        acc[j] += __shfl_xor(acc[j], 32);
    }
    for (; e < e1; ++e) {  // scalar tail: all lanes process same edge
        int s = csrc[e];
        float2 ls = al2[s];
        uint4 r = *(const uint4*)(hbf + (size_t)s * 64 + sub * 4);
        float c = fast_tanh(ls.x + arn) * ls.y * disn;
        acc[0] += c * bf_lo(r.x); acc[1] += c * bf_hi(r.x);
        acc[2] += c * bf_lo(r.y); acc[3] += c * bf_hi(r.y);
        acc[4] += c * bf_lo(r.z); acc[5] += c * bf_hi(r.z);
        acc[6] += c * bf_lo(r.w); acc[7] += c * bf_hi(r.w);
    }
    {   // self loop: coef = tanh(al+ar)*dis^2
        float c = fast_tanh(selfld.x + arn) * disn * disn;
        uint4 r = *(const uint4*)(hbf + (size_t)node * 64 + sub * 4);
        acc[0] += c * bf_lo(r.x); acc[1] += c * bf_hi(r.x);
        acc[2] += c * bf_lo(r.y); acc[3] += c * bf_hi(r.y);
        acc[4] += c * bf_lo(r.z); acc[5] += c * bf_hi(r.z);
        acc[6] += c * bf_lo(r.w); acc[7] += c * bf_hi(r.w);
    }
    float o[8];
    {
        float4 rv0 = *(const float4*)(raw + (size_t)node * HIDDEN + sub * 8);
        float4 rv1 = *(const float4*)(raw + (size_t)node * HIDDEN + sub * 8 + 4);
        o[0] = acc[0] + 0.3f * rv0.x; o[1] = acc[1] + 0.3f * rv0.y;
        o[2] = acc[2] + 0.3f * rv0.z; o[3] = acc[3] + 0.3f * rv0.w;
        o[4] = acc[4] + 0.3f * rv1.x; o[5] = acc[5] + 0.3f * rv1.y;
        o[6] = acc[6] + 0.3f * rv1.z; o[7] = acc[7] + 0.3f * rv1.w;
    }
    if (grp == 0) {
        *(float4*)(hout + (size_t)node * HIDDEN + sub * 8) = make_float4(o[0], o[1], o[2], o[3]);
        *(float4*)(hout + (size_t)node * HIDDEN + sub * 8 + 4) = make_float4(o[4], o[5], o[6], o[7]);
        if (houtbf) {
            uint4 pk = make_uint4(pack_bf16(o[0], o[1]), pack_bf16(o[2], o[3]),
                                  pack_bf16(o[4], o[5]), pack_bf16(o[6], o[7]));
            *(uint4*)(houtbf + (size_t)node * 64 + sub * 4) = pk;
        }
    }
    if (attl_n) {  // fused dots for NEXT layer -> double-buffered al2/ar
        float4 a0 = *(const float4*)(attl_n + sub * 8);
        float4 a1 = *(const float4*)(attl_n + sub * 8 + 4);
        float4 c0 = *(const float4*)(attr_n + sub * 8);
        float4 c1 = *(const float4*)(attr_n + sub * 8 + 4);
        float pl = o[0] * a0.x + o[1] * a0.y + o[2] * a0.z + o[3] * a0.w +
                   o[4] * a1.x + o[5] * a1.y + o[6] * a1.z + o[7] * a1.w;
        float pr = o[0] * c0.x + o[1] * c0.y + o[2] * c0.z + o[3] * c0.w +
                   o[4] * c1.x + o[5] * c1.y + o[6] * c1.z + o[7] * c1.w;
        for (int off = 8; off; off >>= 1) {
            pl += __shfl_xor(pl, off);
            pr += __shfl_xor(pr, off);
        }
        if (lane == 0) {
            al2_o[node] = make_float2(pl, disn);
            ar_o[node] = pr;
        }
    }
}

// ---------------- output: log_softmax(h @ W2^T + b2) ---------------------------
__global__ __launch_bounds__(256) void k_out(const float* __restrict__ h,
                                             const float* __restrict__ W2,
                                             const float* __restrict__ b2,
                                             float* __restrict__ out, int n) {
    __shared__ float ws[NCLASS * HIDDEN];
    __shared__ float bs[NCLASS];
    const int tid = threadIdx.x;
    for (int i = tid; i < NCLASS * HIDDEN / 4; i += 256)
        ((float4*)ws)[i] = ((const float4*)W2)[i];
    if (tid < NCLASS) bs[tid] = b2[tid];
    __syncthreads();
    int node = blockIdx.x * 256 + tid;
    if (node >= n) return;
    const float* hr = h + (size_t)node * HIDDEN;
    float acc[NCLASS];
#pragma unroll
    for (int c = 0; c < NCLASS; ++c) acc[c] = bs[c];
#pragma unroll
    for (int k0 = 0; k0 < HIDDEN; k0 += 16) {
        float4 h0 = *(const float4*)(hr + k0);
        float4 h1 = *(const float4*)(hr + k0 + 4);
        float4 h2 = *(const float4*)(hr + k0 + 8);
        float4 h3 = *(const float4*)(hr + k0 + 12);
#pragma unroll
        for (int c = 0; c < NCLASS; ++c) {
            const float* w = ws + c * HIDDEN + k0;
            float4 w0 = *(const float4*)(w);
            float4 w1 = *(const float4*)(w + 4);
            float4 w2v = *(const float4*)(w + 8);
            float4 w3 = *(const float4*)(w + 12);
            acc[c] += h0.x * w0.x + h0.y * w0.y + h0.z * w0.z + h0.w * w0.w +
                      h1.x * w1.x + h1.y * w1.y + h1.z * w1.z + h1.w * w1.w +
                      h2.x * w2v.x + h2.y * w2v.y + h2.z * w2v.z + h2.w * w2v.w +
                      h3.x * w3.x + h3.y * w3.y + h3.z * w3.z + h3.w * w3.w;
        }
    }
    float m = -INFINITY;
#pragma unroll
    for (int c = 0; c < NCLASS; ++c) m = fmaxf(m, acc[c]);
    float ssum = 0.f;
#pragma unroll
    for (int c = 0; c < NCLASS; ++c) ssum += expf(acc[c] - m);
    float lse = m + logf(ssum);
    float* orow = out + (size_t)node * NCLASS;
#pragma unroll
    for (int c = 0; c < NCLASS; ++c) orow[c] = acc[c] - lse;
}

extern "C" void kernel_launch(void* const* d_in, const int* in_sizes, int n_in,
                              void* d_out, int out_size, void* d_ws, size_t ws_size,
                              hipStream_t stream) {
    const float* x    = (const float*)d_in[0];
    const int*   ei   = (const int*)d_in[1];
    const float* W1   = (const float*)d_in[2];
    const float* b1   = (const float*)d_in[3];
    const float* W2   = (const float*)d_in[4];
    const float* b2   = (const float*)d_in[5];
    const float* attl = (const float*)d_in[6];
    const float* attr = (const float*)d_in[7];
    const int N = in_sizes[0] / FEAT;
    const int E = in_sizes[1] / 2;
    float* out = (float*)d_out;

    char* p = (char*)d_ws;
    auto take = [&](size_t bytes) {
        void* q = (void*)p;
        p += (bytes + 255) & ~(size_t)255;
        return q;
    };
    float*    h0   = (float*)take((size_t)N * HIDDEN * 4);  // = raw, never overwritten
    float*    h1   = (float*)take((size_t)N * HIDDEN * 4);
    float*    h2   = (float*)take((size_t)N * HIDDEN * 4);
    unsigned* hb0  = (unsigned*)take((size_t)N * 64 * 4);
    unsigned* hb1  = (unsigned*)take((size_t)N * 64 * 4);
    int*      deg  = (int*)take((size_t)N * 4);
    float*    dis  = (float*)take((size_t)N * 4);
    int*      offs = (int*)take((size_t)(N + 1) * 4);
    int*      cur  = (int*)take((size_t)N * 4);
    int*      csrc = (int*)take((size_t)E * 4);
    float2*   al2A = (float2*)take((size_t)N * 8);
    float2*   al2B = (float2*)take((size_t)N * 8);
    float*    arA  = (float*)take((size_t)N * 4);
    float*    arB  = (float*)take((size_t)N * 4);
    int*      part = (int*)take(1024);

    hipMemsetAsync(deg, 0, (size_t)N * 4, stream);

    const int ebl = (E + 255) / 256;
    const int nbl = (N + 255) / 256;

    k_degree<<<ebl, 256, 0, stream>>>(ei, E, deg);
    k_dis<<<nbl, 256, 0, stream>>>(deg, dis, N);
    k_scan1<<<nbl, 256, 0, stream>>>(deg, offs, part, N);
    k_scan2<<<1, 256, 0, stream>>>(part, nbl);
    k_scan3<<<nbl, 256, 0, stream>>>(offs, part, N, E);
    hipMemcpyAsync(cur, offs, (size_t)N * 4, hipMemcpyDeviceToDevice, stream);
    k_csr_fill<<<ebl, 256, 0, stream>>>(ei, E, cur, csrc);

    k_gemm1<<<(N + 127) / 128, 256, 0, stream>>>(x, W1, b1, h0, N);
    k_prep<<<(N + 3) / 4, 256, 0, stream>>>(h0, hb0, attl, attr, dis, al2A, arA, N);

    float*    fout[4] = {h1, h2, h1, h2};
    unsigned* hbin = hb0, *hbout = hb1;
    float2*   alin = al2A, *alout = al2B;
    float*    arin = arA,  *arout = arB;
    for (int l = 0; l < 4; ++l) {
        const float* attl_n = (l < 3) ? (attl + (l + 1) * HIDDEN) : nullptr;
        const float* attr_n = (l < 3) ? (attr + (l + 1) * HIDDEN) : nullptr;
        unsigned* hbo = (l < 3) ? hbout : nullptr;
        k_aggregate<<<(N + 3) / 4, 256, 0, stream>>>(hbin, h0, alin, arin, offs, csrc,
                                                     fout[l], hbo, attl_n, attr_n,
                                                     alout, arout, N);
        unsigned* tb = hbin; hbin = hbout; hbout = tb;
        float2* ta = alin; alin = alout; alout = ta;
        float* tr = arin; arin = arout; arout = tr;
    }

    k_out<<<(N + 255) / 256, 256, 0, stream>>>(h2, W2, b2, out, N);
}

// Round 6
// 635.785 us; speedup vs baseline: 2.0681x; 1.1029x over previous
//
#include <hip/hip_runtime.h>
#include <cmath>

// FAGCN: N=50000, E=1.6M, FEAT=512, HIDDEN=128, CLASS=40, 4 layers, eps=0.3
// R6: atomic-free CSR fill via rank trick (k_degree records atomicAdd return as
// rank[e]; fill computes pos = offs[dst]+rank[e] with no atomic round trip).
// Aggregate edge loop unrolled to 16 (4 row-loads in flight per lane).

#define HIDDEN 128
#define FEAT 512
#define NCLASS 40
#define LDST 40  // LDS row stride in ushorts (80 B)

typedef __attribute__((ext_vector_type(8))) short short8;
typedef __attribute__((ext_vector_type(4))) float f32x4;

__device__ __forceinline__ float bf_lo(unsigned u) { return __uint_as_float(u << 16); }
__device__ __forceinline__ float bf_hi(unsigned u) { return __uint_as_float(u & 0xffff0000u); }
__device__ __forceinline__ unsigned pack_bf16(float x, float y) {
    unsigned ux = __float_as_uint(x);
    unsigned uy = __float_as_uint(y);
    unsigned lx = (ux + 0x7fffu + ((ux >> 16) & 1u)) >> 16;
    unsigned hy = (uy + 0x7fffu + ((uy >> 16) & 1u)) & 0xffff0000u;
    return hy | lx;
}
__device__ __forceinline__ float fast_tanh(float x) {
    x = fminf(fmaxf(x, -15.f), 15.f);
    float e = __expf(2.f * x);
    return (e - 1.f) / (e + 1.f);
}

// ---------------- degree + per-edge rank (atomic return value recorded) --------
__global__ void k_degree(const int* __restrict__ ei, int E, int* __restrict__ deg,
                         int* __restrict__ rank) {
    int e = blockIdx.x * 256 + threadIdx.x;
    if (e < E) rank[e] = atomicAdd(&deg[ei[E + e]], 1);
}

__global__ void k_dis(const int* __restrict__ deg, float* __restrict__ dis, int n) {
    int i = blockIdx.x * 256 + threadIdx.x;
    if (i < n) dis[i] = rsqrtf((float)(deg[i] + 1));
}

// ---------------- exclusive scan ----------------
__global__ void k_scan1(const int* __restrict__ deg, int* __restrict__ offs,
                        int* __restrict__ part, int n) {
    __shared__ int s[256];
    int tid = threadIdx.x;
    int gid = blockIdx.x * 256 + tid;
    int v = (gid < n) ? deg[gid] : 0;
    s[tid] = v;
    __syncthreads();
    for (int off = 1; off < 256; off <<= 1) {
        int t = (tid >= off) ? s[tid - off] : 0;
        __syncthreads();
        s[tid] += t;
        __syncthreads();
    }
    if (gid < n) offs[gid] = s[tid] - v;
    if (tid == 255) part[blockIdx.x] = s[255];
}

__global__ void k_scan2(int* __restrict__ part, int nb) {
    __shared__ int s[256];
    int tid = threadIdx.x;
    int v = (tid < nb) ? part[tid] : 0;
    s[tid] = v;
    __syncthreads();
    for (int off = 1; off < 256; off <<= 1) {
        int t = (tid >= off) ? s[tid - off] : 0;
        __syncthreads();
        s[tid] += t;
        __syncthreads();
    }
    if (tid < nb) part[tid] = s[tid] - v;
}

__global__ void k_scan3(int* __restrict__ offs, const int* __restrict__ part, int n, int E) {
    int gid = blockIdx.x * 256 + threadIdx.x;
    if (gid < n) offs[gid] += part[blockIdx.x];
    if (gid == 0) offs[n] = E;
}

// ---------------- CSR fill: NO atomics, pure dataflow ----------------
__global__ void k_csr_fill(const int* __restrict__ ei, int E,
                           const int* __restrict__ offs, const int* __restrict__ rank,
                           int* __restrict__ csrc) {
    int e = blockIdx.x * 256 + threadIdx.x;
    if (e >= E) return;
    int src = ei[e];
    int dst = ei[E + e];
    csrc[offs[dst] + rank[e]] = src;
}

// ---------------- GEMM1: h = relu(x @ W1^T + b1), MFMA bf16 -------------------
__global__ __launch_bounds__(256) void k_gemm1(const float* __restrict__ x,
                                               const float* __restrict__ W1,
                                               const float* __restrict__ b1,
                                               float* __restrict__ h, int M) {
    __shared__ ushort As[128 * LDST];
    __shared__ ushort Bs[128 * LDST];
    const int tid = threadIdx.x;
    const int bm = blockIdx.x * 128;
    const int wave = tid >> 6, lane = tid & 63;
    const int rh = (wave >> 1) * 64;
    const int ch = (wave & 1) * 64;
    const int sub = lane & 15, quad = lane >> 4;
    const int lrow = tid >> 3;
    const int lcol = (tid & 7) * 4;
    f32x4 acc[4][4] = {};
    for (int k0 = 0; k0 < FEAT; k0 += 32) {
#pragma unroll
        for (int i = 0; i < 4; ++i) {
            int r = lrow + 32 * i;
            int grow = bm + r;
            float4 v = make_float4(0.f, 0.f, 0.f, 0.f);
            if (grow < M) v = *(const float4*)(x + (size_t)grow * FEAT + k0 + lcol);
            uint2 pk = make_uint2(pack_bf16(v.x, v.y), pack_bf16(v.z, v.w));
            *(uint2*)(As + r * LDST + lcol) = pk;
        }
#pragma unroll
        for (int i = 0; i < 4; ++i) {
            int r = lrow + 32 * i;
            float4 v = *(const float4*)(W1 + (size_t)r * FEAT + k0 + lcol);
            uint2 pk = make_uint2(pack_bf16(v.x, v.y), pack_bf16(v.z, v.w));
            *(uint2*)(Bs + r * LDST + lcol) = pk;
        }
        __syncthreads();
        short8 af[4], bfr[4];
#pragma unroll
        for (int t = 0; t < 4; ++t)
            af[t] = *(const short8*)(As + (rh + t * 16 + sub) * LDST + quad * 8);
#pragma unroll
        for (int u = 0; u < 4; ++u)
            bfr[u] = *(const short8*)(Bs + (ch + u * 16 + sub) * LDST + quad * 8);
#pragma unroll
        for (int t = 0; t < 4; ++t)
#pragma unroll
            for (int u = 0; u < 4; ++u)
                acc[t][u] = __builtin_amdgcn_mfma_f32_16x16x32_bf16(af[t], bfr[u], acc[t][u], 0, 0, 0);
        __syncthreads();
    }
    float b1v[4];
#pragma unroll
    for (int u = 0; u < 4; ++u) b1v[u] = b1[ch + u * 16 + sub];
#pragma unroll
    for (int t = 0; t < 4; ++t) {
#pragma unroll
        for (int u = 0; u < 4; ++u) {
            int col = ch + u * 16 + sub;
#pragma unroll
            for (int r2 = 0; r2 < 4; ++r2) {
                int grow = bm + rh + t * 16 + quad * 4 + r2;
                if (grow < M)
                    h[(size_t)grow * HIDDEN + col] = fmaxf(acc[t][u][r2] + b1v[u], 0.f);
            }
        }
    }
}

// ---------------- prep: bf16 pack + layer-0 dots -> {al,dis}, ar ----------------
__global__ void k_prep(const float* __restrict__ h, unsigned* __restrict__ hbf,
                       const float* __restrict__ attl, const float* __restrict__ attr,
                       const float* __restrict__ dis, float2* __restrict__ al2,
                       float* __restrict__ ar, int n) {
    int node = (blockIdx.x * blockDim.x + threadIdx.x) >> 6;
    int lane = threadIdx.x & 63;
    if (node >= n) return;
    float2 hv = ((const float2*)(h + (size_t)node * HIDDEN))[lane];
    hbf[(size_t)node * 64 + lane] = pack_bf16(hv.x, hv.y);
    float pl = hv.x * attl[2 * lane] + hv.y * attl[2 * lane + 1];
    float pr = hv.x * attr[2 * lane] + hv.y * attr[2 * lane + 1];
    for (int off = 32; off; off >>= 1) {
        pl += __shfl_down(pl, off);
        pr += __shfl_down(pr, off);
    }
    if (lane == 0) {
        al2[node] = make_float2(pl, dis[node]);
        ar[node] = pr;
    }
}

// ---------------- aggregate with inline coef, 16-edge unroll --------------------
__global__ void k_aggregate(const unsigned* __restrict__ hbf, const float* __restrict__ raw,
                            const float2* __restrict__ al2, const float* __restrict__ ar,
                            const int* __restrict__ offs, const int* __restrict__ csrc,
                            float* __restrict__ hout, unsigned* __restrict__ houtbf,
                            const float* __restrict__ attl_n, const float* __restrict__ attr_n,
                            float2* __restrict__ al2_o, float* __restrict__ ar_o, int n) {
    int node = (blockIdx.x * blockDim.x + threadIdx.x) >> 6;
    int lane = threadIdx.x & 63;
    if (node >= n) return;
    const int grp = lane >> 4;
    const int sub = lane & 15;
    const float arn = ar[node];
    const float2 selfld = al2[node];
    const float disn = selfld.y;
    float acc[8] = {0.f, 0.f, 0.f, 0.f, 0.f, 0.f, 0.f, 0.f};
    int e0 = offs[node], e1 = offs[node + 1];
    int e = e0;
    // 16 edges per iteration: 4 independent row-loads in flight per lane
    for (; e + 16 <= e1; e += 16) {
        int sa = csrc[e + grp];
        int sb = csrc[e + 4 + grp];
        int sc = csrc[e + 8 + grp];
        int sd = csrc[e + 12 + grp];
        float2 la = al2[sa];
        float2 lb = al2[sb];
        float2 lc = al2[sc];
        float2 ld = al2[sd];
        uint4 ra = *(const uint4*)(hbf + (size_t)sa * 64 + sub * 4);
        uint4 rb = *(const uint4*)(hbf + (size_t)sb * 64 + sub * 4);
        uint4 rc = *(const uint4*)(hbf + (size_t)sc * 64 + sub * 4);
        uint4 rd = *(const uint4*)(hbf + (size_t)sd * 64 + sub * 4);
        float ca = fast_tanh(la.x + arn) * la.y * disn;
        float cb = fast_tanh(lb.x + arn) * lb.y * disn;
        float cc = fast_tanh(lc.x + arn) * lc.y * disn;
        float cd = fast_tanh(ld.x + arn) * ld.y * disn;
        acc[0] += ca * bf_lo(ra.x); acc[1] += ca * bf_hi(ra.x);
        acc[2] += ca * bf_lo(ra.y); acc[3] += ca * bf_hi(ra.y);
        acc[4] += ca * bf_lo(ra.z); acc[5] += ca * bf_hi(ra.z);
        acc[6] += ca * bf_lo(ra.w); acc[7] += ca * bf_hi(ra.w);
        acc[0] += cb * bf_lo(rb.x); acc[1] += cb * bf_hi(rb.x);
        acc[2] += cb * bf_lo(rb.y); acc[3] += cb * bf_hi(rb.y);
        acc[4] += cb * bf_lo(rb.z); acc[5] += cb * bf_hi(rb.z);
        acc[6] += cb * bf_lo(rb.w); acc[7] += cb * bf_hi(rb.w);
        acc[0] += cc * bf_lo(rc.x); acc[1] += cc * bf_hi(rc.x);
        acc[2] += cc * bf_lo(rc.y); acc[3] += cc * bf_hi(rc.y);
        acc[4] += cc * bf_lo(rc.z); acc[5] += cc * bf_hi(rc.z);
        acc[6] += cc * bf_lo(rc.w); acc[7] += cc * bf_hi(rc.w);
        acc[0] += cd * bf_lo(rd.x); acc[1] += cd * bf_hi(rd.x);
        acc[2] += cd * bf_lo(rd.y); acc[3] += cd * bf_hi(rd.y);
        acc[4] += cd * bf_lo(rd.z); acc[5] += cd * bf_hi(rd.z);
        acc[6] += cd * bf_lo(rd.w); acc[7] += cd * bf_hi(rd.w);
    }
    for (; e + 8 <= e1; e += 8) {
        int sa = csrc[e + grp];
        int sb = csrc[e + 4 + grp];
        float2 la = al2[sa];
        float2 lb = al2[sb];
        uint4 ra = *(const uint4*)(hbf + (size_t)sa * 64 + sub * 4);
        uint4 rb = *(const uint4*)(hbf + (size_t)sb * 64 + sub * 4);
        float ca = fast_tanh(la.x + arn) * la.y * disn;
        float cb = fast_tanh(lb.x + arn) * lb.y * disn;
        acc[0] += ca * bf_lo(ra.x); acc[1] += ca * bf_hi(ra.x);
        acc[2] += ca * bf_lo(ra.y); acc[3] += ca * bf_hi(ra.y);
        acc[4] += ca * bf_lo(ra.z); acc[5] += ca * bf_hi(ra.z);
        acc[6] += ca * bf_lo(ra.w); acc[7] += ca * bf_hi(ra.w);
        acc[0] += cb * bf_lo(rb.x); acc[1] += cb * bf_hi(rb.x);
        acc[2] += cb * bf_lo(rb.y); acc[3] += cb * bf_hi(rb.y);
        acc[4] += cb * bf_lo(rb.z); acc[5] += cb * bf_hi(rb.z);
        acc[6] += cb * bf_lo(rb.w); acc[7] += cb * bf_hi(rb.w);
    }
    for (; e + 4 <= e1; e += 4) {
        int sa = csrc[e + grp];
        float2 la = al2[sa];
        uint4 ra = *(const uint4*)(hbf + (size_t)sa * 64 + sub * 4);
        float ca = fast_tanh(la.x + arn) * la.y * disn;
        acc[0] += ca * bf_lo(ra.x); acc[1] += ca * bf_hi(ra.x);
        acc[2] += ca * bf_lo(ra.y); acc[3] += ca * bf_hi(ra.y);
        acc[4] += ca * bf_lo(ra.z); acc[5] += ca * bf_hi(ra.z);
        acc[6] += ca * bf_lo(ra.w); acc[7] += ca * bf_hi(ra.w);
    }
#pragma unroll
    for (int j = 0; j < 8; ++j) {
        acc[j] += __shfl_xor(acc[j], 16);
        acc[j] += __shfl_xor(acc[j], 32);
    }
    for (; e < e1; ++e) {
        int s = csrc[e];
        float2 ls = al2[s];
        uint4 r = *(const uint4*)(hbf + (size_t)s * 64 + sub * 4);
        float c = fast_tanh(ls.x + arn) * ls.y * disn;
        acc[0] += c * bf_lo(r.x); acc[1] += c * bf_hi(r.x);
        acc[2] += c * bf_lo(r.y); acc[3] += c * bf_hi(r.y);
        acc[4] += c * bf_lo(r.z); acc[5] += c * bf_hi(r.z);
        acc[6] += c * bf_lo(r.w); acc[7] += c * bf_hi(r.w);
    }
    {
        float c = fast_tanh(selfld.x + arn) * disn * disn;
        uint4 r = *(const uint4*)(hbf + (size_t)node * 64 + sub * 4);
        acc[0] += c * bf_lo(r.x); acc[1] += c * bf_hi(r.x);
        acc[2] += c * bf_lo(r.y); acc[3] += c * bf_hi(r.y);
        acc[4] += c * bf_lo(r.z); acc[5] += c * bf_hi(r.z);
        acc[6] += c * bf_lo(r.w); acc[7] += c * bf_hi(r.w);
    }
    float o[8];
    {
        float4 rv0 = *(const float4*)(raw + (size_t)node * HIDDEN + sub * 8);
        float4 rv1 = *(const float4*)(raw + (size_t)node * HIDDEN + sub * 8 + 4);
        o[0] = acc[0] + 0.3f * rv0.x; o[1] = acc[1] + 0.3f * rv0.y;
        o[2] = acc[2] + 0.3f * rv0.z; o[3] = acc[3] + 0.3f * rv0.w;
        o[4] = acc[4] + 0.3f * rv1.x; o[5] = acc[5] + 0.3f * rv1.y;
        o[6] = acc[6] + 0.3f * rv1.z; o[7] = acc[7] + 0.3f * rv1.w;
    }
    if (grp == 0) {
        *(float4*)(hout + (size_t)node * HIDDEN + sub * 8) = make_float4(o[0], o[1], o[2], o[3]);
        *(float4*)(hout + (size_t)node * HIDDEN + sub * 8 + 4) = make_float4(o[4], o[5], o[6], o[7]);
        if (houtbf) {
            uint4 pk = make_uint4(pack_bf16(o[0], o[1]), pack_bf16(o[2], o[3]),
                                  pack_bf16(o[4], o[5]), pack_bf16(o[6], o[7]));
            *(uint4*)(houtbf + (size_t)node * 64 + sub * 4) = pk;
        }
    }
    if (attl_n) {
        float4 a0 = *(const float4*)(attl_n + sub * 8);
        float4 a1 = *(const float4*)(attl_n + sub * 8 + 4);
        float4 c0 = *(const float4*)(attr_n + sub * 8);
        float4 c1 = *(const float4*)(attr_n + sub * 8 + 4);
        float pl = o[0] * a0.x + o[1] * a0.y + o[2] * a0.z + o[3] * a0.w +
                   o[4] * a1.x + o[5] * a1.y + o[6] * a1.z + o[7] * a1.w;
        float pr = o[0] * c0.x + o[1] * c0.y + o[2] * c0.z + o[3] * c0.w +
                   o[4] * c1.x + o[5] * c1.y + o[6] * c1.z + o[7] * c1.w;
        for (int off = 8; off; off >>= 1) {
            pl += __shfl_xor(pl, off);
            pr += __shfl_xor(pr, off);
        }
        if (lane == 0) {
            al2_o[node] = make_float2(pl, disn);
            ar_o[node] = pr;
        }
    }
}

// ---------------- output: log_softmax(h @ W2^T + b2) ---------------------------
__global__ __launch_bounds__(256) void k_out(const float* __restrict__ h,
                                             const float* __restrict__ W2,
                                             const float* __restrict__ b2,
                                             float* __restrict__ out, int n) {
    __shared__ float ws[NCLASS * HIDDEN];
    __shared__ float bs[NCLASS];
    const int tid = threadIdx.x;
    for (int i = tid; i < NCLASS * HIDDEN / 4; i += 256)
        ((float4*)ws)[i] = ((const float4*)W2)[i];
    if (tid < NCLASS) bs[tid] = b2[tid];
    __syncthreads();
    int node = blockIdx.x * 256 + tid;
    if (node >= n) return;
    const float* hr = h + (size_t)node * HIDDEN;
    float acc[NCLASS];
#pragma unroll
    for (int c = 0; c < NCLASS; ++c) acc[c] = bs[c];
#pragma unroll
    for (int k0 = 0; k0 < HIDDEN; k0 += 16) {
        float4 h0 = *(const float4*)(hr + k0);
        float4 h1 = *(const float4*)(hr + k0 + 4);
        float4 h2 = *(const float4*)(hr + k0 + 8);
        float4 h3 = *(const float4*)(hr + k0 + 12);
#pragma unroll
        for (int c = 0; c < NCLASS; ++c) {
            const float* w = ws + c * HIDDEN + k0;
            float4 w0 = *(const float4*)(w);
            float4 w1 = *(const float4*)(w + 4);
            float4 w2v = *(const float4*)(w + 8);
            float4 w3 = *(const float4*)(w + 12);
            acc[c] += h0.x * w0.x + h0.y * w0.y + h0.z * w0.z + h0.w * w0.w +
                      h1.x * w1.x + h1.y * w1.y + h1.z * w1.z + h1.w * w1.w +
                      h2.x * w2v.x + h2.y * w2v.y + h2.z * w2v.z + h2.w * w2v.w +
                      h3.x * w3.x + h3.y * w3.y + h3.z * w3.z + h3.w * w3.w;
        }
    }
    float m = -INFINITY;
#pragma unroll
    for (int c = 0; c < NCLASS; ++c) m = fmaxf(m, acc[c]);
    float ssum = 0.f;
#pragma unroll
    for (int c = 0; c < NCLASS; ++c) ssum += expf(acc[c] - m);
    float lse = m + logf(ssum);
    float* orow = out + (size_t)node * NCLASS;
#pragma unroll
    for (int c = 0; c < NCLASS; ++c) orow[c] = acc[c] - lse;
}

extern "C" void kernel_launch(void* const* d_in, const int* in_sizes, int n_in,
                              void* d_out, int out_size, void* d_ws, size_t ws_size,
                              hipStream_t stream) {
    const float* x    = (const float*)d_in[0];
    const int*   ei   = (const int*)d_in[1];
    const float* W1   = (const float*)d_in[2];
    const float* b1   = (const float*)d_in[3];
    const float* W2   = (const float*)d_in[4];
    const float* b2   = (const float*)d_in[5];
    const float* attl = (const float*)d_in[6];
    const float* attr = (const float*)d_in[7];
    const int N = in_sizes[0] / FEAT;
    const int E = in_sizes[1] / 2;
    float* out = (float*)d_out;

    char* p = (char*)d_ws;
    auto take = [&](size_t bytes) {
        void* q = (void*)p;
        p += (bytes + 255) & ~(size_t)255;
        return q;
    };
    float*    h0   = (float*)take((size_t)N * HIDDEN * 4);  // = raw
    float*    h1   = (float*)take((size_t)N * HIDDEN * 4);
    float*    h2   = (float*)take((size_t)N * HIDDEN * 4);
    unsigned* hb0  = (unsigned*)take((size_t)N * 64 * 4);
    unsigned* hb1  = (unsigned*)take((size_t)N * 64 * 4);
    int*      deg  = (int*)take((size_t)N * 4);
    float*    dis  = (float*)take((size_t)N * 4);
    int*      offs = (int*)take((size_t)(N + 1) * 4);
    int*      rank = (int*)take((size_t)E * 4);
    int*      csrc = (int*)take((size_t)E * 4);
    float2*   al2A = (float2*)take((size_t)N * 8);
    float2*   al2B = (float2*)take((size_t)N * 8);
    float*    arA  = (float*)take((size_t)N * 4);
    float*    arB  = (float*)take((size_t)N * 4);
    int*      part = (int*)take(1024);

    hipMemsetAsync(deg, 0, (size_t)N * 4, stream);

    const int ebl = (E + 255) / 256;
    const int nbl = (N + 255) / 256;

    k_degree<<<ebl, 256, 0, stream>>>(ei, E, deg, rank);
    k_dis<<<nbl, 256, 0, stream>>>(deg, dis, N);
    k_scan1<<<nbl, 256, 0, stream>>>(deg, offs, part, N);
    k_scan2<<<1, 256, 0, stream>>>(part, nbl);
    k_scan3<<<nbl, 256, 0, stream>>>(offs, part, N, E);
    k_csr_fill<<<ebl, 256, 0, stream>>>(ei, E, offs, rank, csrc);

    k_gemm1<<<(N + 127) / 128, 256, 0, stream>>>(x, W1, b1, h0, N);
    k_prep<<<(N + 3) / 4, 256, 0, stream>>>(h0, hb0, attl, attr, dis, al2A, arA, N);

    float*    fout[4] = {h1, h2, h1, h2};
    unsigned* hbin = hb0, *hbout = hb1;
    float2*   alin = al2A, *alout = al2B;
    float*    arin = arA,  *arout = arB;
    for (int l = 0; l < 4; ++l) {
        const float* attl_n = (l < 3) ? (attl + (l + 1) * HIDDEN) : nullptr;
        const float* attr_n = (l < 3) ? (attr + (l + 1) * HIDDEN) : nullptr;
        unsigned* hbo = (l < 3) ? hbout : nullptr;
        k_aggregate<<<(N + 3) / 4, 256, 0, stream>>>(hbin, h0, alin, arin, offs, csrc,
                                                     fout[l], hbo, attl_n, attr_n,
                                                     alout, arout, N);
        unsigned* tb = hbin; hbin = hbout; hbout = tb;
        float2* ta = alin; alin = alout; alout = ta;
        float* tr = arin; arin = arout; arout = tr;
    }

    k_out<<<(N + 255) / 256, 256, 0, stream>>>(h2, W2, b2, out, N);
}

// Round 7
// 628.515 us; speedup vs baseline: 2.0920x; 1.0116x over previous
//
#include <hip/hip_runtime.h>
#include <cmath>

// FAGCN: N=50000, E=1.6M, FEAT=512, HIDDEN=128, CLASS=40, 4 layers, eps=0.3
// R7: k_degree unrolled 8 edges/thread (8 independent atomics in flight);
// csr_fill unrolled x4; aggregate computes each edge coef ONCE (lane sub owns
// edge e+sub) and broadcasts {src,coef} via shuffle (DS pipe) - kills the 16x
// redundant tanh.

#define HIDDEN 128
#define FEAT 512
#define NCLASS 40
#define LDST 40  // LDS row stride in ushorts (80 B)

typedef __attribute__((ext_vector_type(8))) short short8;
typedef __attribute__((ext_vector_type(4))) float f32x4;

__device__ __forceinline__ float bf_lo(unsigned u) { return __uint_as_float(u << 16); }
__device__ __forceinline__ float bf_hi(unsigned u) { return __uint_as_float(u & 0xffff0000u); }
__device__ __forceinline__ unsigned pack_bf16(float x, float y) {
    unsigned ux = __float_as_uint(x);
    unsigned uy = __float_as_uint(y);
    unsigned lx = (ux + 0x7fffu + ((ux >> 16) & 1u)) >> 16;
    unsigned hy = (uy + 0x7fffu + ((uy >> 16) & 1u)) & 0xffff0000u;
    return hy | lx;
}
__device__ __forceinline__ float fast_tanh(float x) {
    x = fminf(fmaxf(x, -15.f), 15.f);
    float e = __expf(2.f * x);
    return (e - 1.f) / (e + 1.f);
}

// ---------------- degree + rank: 8 edges/thread, independent atomics -----------
__global__ void k_degree(const int* __restrict__ ei, int E, int* __restrict__ deg,
                         int* __restrict__ rank) {
    int base = blockIdx.x * 2048 + threadIdx.x;
    int r[8];
    int e[8];
#pragma unroll
    for (int i = 0; i < 8; ++i) {
        e[i] = base + 256 * i;
        if (e[i] < E) r[i] = atomicAdd(&deg[ei[E + e[i]]], 1);
    }
#pragma unroll
    for (int i = 0; i < 8; ++i)
        if (e[i] < E) rank[e[i]] = r[i];
}

__global__ void k_dis(const int* __restrict__ deg, float* __restrict__ dis, int n) {
    int i = blockIdx.x * 256 + threadIdx.x;
    if (i < n) dis[i] = rsqrtf((float)(deg[i] + 1));
}

// ---------------- exclusive scan ----------------
__global__ void k_scan1(const int* __restrict__ deg, int* __restrict__ offs,
                        int* __restrict__ part, int n) {
    __shared__ int s[256];
    int tid = threadIdx.x;
    int gid = blockIdx.x * 256 + tid;
    int v = (gid < n) ? deg[gid] : 0;
    s[tid] = v;
    __syncthreads();
    for (int off = 1; off < 256; off <<= 1) {
        int t = (tid >= off) ? s[tid - off] : 0;
        __syncthreads();
        s[tid] += t;
        __syncthreads();
    }
    if (gid < n) offs[gid] = s[tid] - v;
    if (tid == 255) part[blockIdx.x] = s[255];
}

__global__ void k_scan2(int* __restrict__ part, int nb) {
    __shared__ int s[256];
    int tid = threadIdx.x;
    int v = (tid < nb) ? part[tid] : 0;
    s[tid] = v;
    __syncthreads();
    for (int off = 1; off < 256; off <<= 1) {
        int t = (tid >= off) ? s[tid - off] : 0;
        __syncthreads();
        s[tid] += t;
        __syncthreads();
    }
    if (tid < nb) part[tid] = s[tid] - v;
}

__global__ void k_scan3(int* __restrict__ offs, const int* __restrict__ part, int n, int E) {
    int gid = blockIdx.x * 256 + threadIdx.x;
    if (gid < n) offs[gid] += part[blockIdx.x];
    if (gid == 0) offs[n] = E;
}

// ---------------- CSR fill: no atomics, 4 edges/thread ----------------
__global__ void k_csr_fill(const int* __restrict__ ei, int E,
                           const int* __restrict__ offs, const int* __restrict__ rank,
                           int* __restrict__ csrc) {
    int base = blockIdx.x * 1024 + threadIdx.x;
#pragma unroll
    for (int i = 0; i < 4; ++i) {
        int e = base + 256 * i;
        if (e < E) csrc[offs[ei[E + e]] + rank[e]] = ei[e];
    }
}

// ---------------- GEMM1: h = relu(x @ W1^T + b1), MFMA bf16 -------------------
__global__ __launch_bounds__(256) void k_gemm1(const float* __restrict__ x,
                                               const float* __restrict__ W1,
                                               const float* __restrict__ b1,
                                               float* __restrict__ h, int M) {
    __shared__ ushort As[128 * LDST];
    __shared__ ushort Bs[128 * LDST];
    const int tid = threadIdx.x;
    const int bm = blockIdx.x * 128;
    const int wave = tid >> 6, lane = tid & 63;
    const int rh = (wave >> 1) * 64;
    const int ch = (wave & 1) * 64;
    const int sub = lane & 15, quad = lane >> 4;
    const int lrow = tid >> 3;
    const int lcol = (tid & 7) * 4;
    f32x4 acc[4][4] = {};
    for (int k0 = 0; k0 < FEAT; k0 += 32) {
#pragma unroll
        for (int i = 0; i < 4; ++i) {
            int r = lrow + 32 * i;
            int grow = bm + r;
            float4 v = make_float4(0.f, 0.f, 0.f, 0.f);
            if (grow < M) v = *(const float4*)(x + (size_t)grow * FEAT + k0 + lcol);
            uint2 pk = make_uint2(pack_bf16(v.x, v.y), pack_bf16(v.z, v.w));
            *(uint2*)(As + r * LDST + lcol) = pk;
        }
#pragma unroll
        for (int i = 0; i < 4; ++i) {
            int r = lrow + 32 * i;
            float4 v = *(const float4*)(W1 + (size_t)r * FEAT + k0 + lcol);
            uint2 pk = make_uint2(pack_bf16(v.x, v.y), pack_bf16(v.z, v.w));
            *(uint2*)(Bs + r * LDST + lcol) = pk;
        }
        __syncthreads();
        short8 af[4], bfr[4];
#pragma unroll
        for (int t = 0; t < 4; ++t)
            af[t] = *(const short8*)(As + (rh + t * 16 + sub) * LDST + quad * 8);
#pragma unroll
        for (int u = 0; u < 4; ++u)
            bfr[u] = *(const short8*)(Bs + (ch + u * 16 + sub) * LDST + quad * 8);
#pragma unroll
        for (int t = 0; t < 4; ++t)
#pragma unroll
            for (int u = 0; u < 4; ++u)
                acc[t][u] = __builtin_amdgcn_mfma_f32_16x16x32_bf16(af[t], bfr[u], acc[t][u], 0, 0, 0);
        __syncthreads();
    }
    float b1v[4];
#pragma unroll
    for (int u = 0; u < 4; ++u) b1v[u] = b1[ch + u * 16 + sub];
#pragma unroll
    for (int t = 0; t < 4; ++t) {
#pragma unroll
        for (int u = 0; u < 4; ++u) {
            int col = ch + u * 16 + sub;
#pragma unroll
            for (int r2 = 0; r2 < 4; ++r2) {
                int grow = bm + rh + t * 16 + quad * 4 + r2;
                if (grow < M)
                    h[(size_t)grow * HIDDEN + col] = fmaxf(acc[t][u][r2] + b1v[u], 0.f);
            }
        }
    }
}

// ---------------- prep: bf16 pack + layer-0 dots -> {al,dis}, ar ----------------
__global__ void k_prep(const float* __restrict__ h, unsigned* __restrict__ hbf,
                       const float* __restrict__ attl, const float* __restrict__ attr,
                       const float* __restrict__ dis, float2* __restrict__ al2,
                       float* __restrict__ ar, int n) {
    int node = (blockIdx.x * blockDim.x + threadIdx.x) >> 6;
    int lane = threadIdx.x & 63;
    if (node >= n) return;
    float2 hv = ((const float2*)(h + (size_t)node * HIDDEN))[lane];
    hbf[(size_t)node * 64 + lane] = pack_bf16(hv.x, hv.y);
    float pl = hv.x * attl[2 * lane] + hv.y * attl[2 * lane + 1];
    float pr = hv.x * attr[2 * lane] + hv.y * attr[2 * lane + 1];
    for (int off = 32; off; off >>= 1) {
        pl += __shfl_down(pl, off);
        pr += __shfl_down(pr, off);
    }
    if (lane == 0) {
        al2[node] = make_float2(pl, dis[node]);
        ar[node] = pr;
    }
}

// ---------------- aggregate: coef computed once/edge, shuffled to groups --------
__global__ void k_aggregate(const unsigned* __restrict__ hbf, const float* __restrict__ raw,
                            const float2* __restrict__ al2, const float* __restrict__ ar,
                            const int* __restrict__ offs, const int* __restrict__ csrc,
                            float* __restrict__ hout, unsigned* __restrict__ houtbf,
                            const float* __restrict__ attl_n, const float* __restrict__ attr_n,
                            float2* __restrict__ al2_o, float* __restrict__ ar_o, int n) {
    int node = (blockIdx.x * blockDim.x + threadIdx.x) >> 6;
    int lane = threadIdx.x & 63;
    if (node >= n) return;
    const int grp = lane >> 4;
    const int sub = lane & 15;
    const float arn = ar[node];
    const float2 selfld = al2[node];
    const float disn = selfld.y;
    float acc[8] = {0.f, 0.f, 0.f, 0.f, 0.f, 0.f, 0.f, 0.f};
    int e0 = offs[node], e1 = offs[node + 1];
    int e = e0;
    // 16 edges/iter: lane `sub` owns edge e+sub (1 csrc load, 1 al2 gather,
    // 1 tanh); {src,coef} broadcast to row-groups via shuffle (DS pipe).
    for (; e + 16 <= e1; e += 16) {
        int smy = csrc[e + sub];
        float2 lmy = al2[smy];
        float cmy = fast_tanh(lmy.x + arn) * lmy.y * disn;
        int sa = __shfl(smy, grp);
        int sb = __shfl(smy, 4 + grp);
        int sc = __shfl(smy, 8 + grp);
        int sd = __shfl(smy, 12 + grp);
        float ca = __shfl(cmy, grp);
        float cb = __shfl(cmy, 4 + grp);
        float cc = __shfl(cmy, 8 + grp);
        float cd = __shfl(cmy, 12 + grp);
        uint4 ra = *(const uint4*)(hbf + (size_t)sa * 64 + sub * 4);
        uint4 rb = *(const uint4*)(hbf + (size_t)sb * 64 + sub * 4);
        uint4 rc = *(const uint4*)(hbf + (size_t)sc * 64 + sub * 4);
        uint4 rd = *(const uint4*)(hbf + (size_t)sd * 64 + sub * 4);
        acc[0] += ca * bf_lo(ra.x); acc[1] += ca * bf_hi(ra.x);
        acc[2] += ca * bf_lo(ra.y); acc[3] += ca * bf_hi(ra.y);
        acc[4] += ca * bf_lo(ra.z); acc[5] += ca * bf_hi(ra.z);
        acc[6] += ca * bf_lo(ra.w); acc[7] += ca * bf_hi(ra.w);
        acc[0] += cb * bf_lo(rb.x); acc[1] += cb * bf_hi(rb.x);
        acc[2] += cb * bf_lo(rb.y); acc[3] += cb * bf_hi(rb.y);
        acc[4] += cb * bf_lo(rb.z); acc[5] += cb * bf_hi(rb.z);
        acc[6] += cb * bf_lo(rb.w); acc[7] += cb * bf_hi(rb.w);
        acc[0] += cc * bf_lo(rc.x); acc[1] += cc * bf_hi(rc.x);
        acc[2] += cc * bf_lo(rc.y); acc[3] += cc * bf_hi(rc.y);
        acc[4] += cc * bf_lo(rc.z); acc[5] += cc * bf_hi(rc.z);
        acc[6] += cc * bf_lo(rc.w); acc[7] += cc * bf_hi(rc.w);
        acc[0] += cd * bf_lo(rd.x); acc[1] += cd * bf_hi(rd.x);
        acc[2] += cd * bf_lo(rd.y); acc[3] += cd * bf_hi(rd.y);
        acc[4] += cd * bf_lo(rd.z); acc[5] += cd * bf_hi(rd.z);
        acc[6] += cd * bf_lo(rd.w); acc[7] += cd * bf_hi(rd.w);
    }
    for (; e + 4 <= e1; e += 4) {
        int sa = csrc[e + grp];
        float2 la = al2[sa];
        uint4 ra = *(const uint4*)(hbf + (size_t)sa * 64 + sub * 4);
        float ca = fast_tanh(la.x + arn) * la.y * disn;
        acc[0] += ca * bf_lo(ra.x); acc[1] += ca * bf_hi(ra.x);
        acc[2] += ca * bf_lo(ra.y); acc[3] += ca * bf_hi(ra.y);
        acc[4] += ca * bf_lo(ra.z); acc[5] += ca * bf_hi(ra.z);
        acc[6] += ca * bf_lo(ra.w); acc[7] += ca * bf_hi(ra.w);
    }
#pragma unroll
    for (int j = 0; j < 8; ++j) {
        acc[j] += __shfl_xor(acc[j], 16);
        acc[j] += __shfl_xor(acc[j], 32);
    }
    for (; e < e1; ++e) {
        int s = csrc[e];
        float2 ls = al2[s];
        uint4 r = *(const uint4*)(hbf + (size_t)s * 64 + sub * 4);
        float c = fast_tanh(ls.x + arn) * ls.y * disn;
        acc[0] += c * bf_lo(r.x); acc[1] += c * bf_hi(r.x);
        acc[2] += c * bf_lo(r.y); acc[3] += c * bf_hi(r.y);
        acc[4] += c * bf_lo(r.z); acc[5] += c * bf_hi(r.z);
        acc[6] += c * bf_lo(r.w); acc[7] += c * bf_hi(r.w);
    }
    {
        float c = fast_tanh(selfld.x + arn) * disn * disn;
        uint4 r = *(const uint4*)(hbf + (size_t)node * 64 + sub * 4);
        acc[0] += c * bf_lo(r.x); acc[1] += c * bf_hi(r.x);
        acc[2] += c * bf_lo(r.y); acc[3] += c * bf_hi(r.y);
        acc[4] += c * bf_lo(r.z); acc[5] += c * bf_hi(r.z);
        acc[6] += c * bf_lo(r.w); acc[7] += c * bf_hi(r.w);
    }
    float o[8];
    {
        float4 rv0 = *(const float4*)(raw + (size_t)node * HIDDEN + sub * 8);
        float4 rv1 = *(const float4*)(raw + (size_t)node * HIDDEN + sub * 8 + 4);
        o[0] = acc[0] + 0.3f * rv0.x; o[1] = acc[1] + 0.3f * rv0.y;
        o[2] = acc[2] + 0.3f * rv0.z; o[3] = acc[3] + 0.3f * rv0.w;
        o[4] = acc[4] + 0.3f * rv1.x; o[5] = acc[5] + 0.3f * rv1.y;
        o[6] = acc[6] + 0.3f * rv1.z; o[7] = acc[7] + 0.3f * rv1.w;
    }
    if (grp == 0) {
        *(float4*)(hout + (size_t)node * HIDDEN + sub * 8) = make_float4(o[0], o[1], o[2], o[3]);
        *(float4*)(hout + (size_t)node * HIDDEN + sub * 8 + 4) = make_float4(o[4], o[5], o[6], o[7]);
        if (houtbf) {
            uint4 pk = make_uint4(pack_bf16(o[0], o[1]), pack_bf16(o[2], o[3]),
                                  pack_bf16(o[4], o[5]), pack_bf16(o[6], o[7]));
            *(uint4*)(houtbf + (size_t)node * 64 + sub * 4) = pk;
        }
    }
    if (attl_n) {
        float4 a0 = *(const float4*)(attl_n + sub * 8);
        float4 a1 = *(const float4*)(attl_n + sub * 8 + 4);
        float4 c0 = *(const float4*)(attr_n + sub * 8);
        float4 c1 = *(const float4*)(attr_n + sub * 8 + 4);
        float pl = o[0] * a0.x + o[1] * a0.y + o[2] * a0.z + o[3] * a0.w +
                   o[4] * a1.x + o[5] * a1.y + o[6] * a1.z + o[7] * a1.w;
        float pr = o[0] * c0.x + o[1] * c0.y + o[2] * c0.z + o[3] * c0.w +
                   o[4] * c1.x + o[5] * c1.y + o[6] * c1.z + o[7] * c1.w;
        for (int off = 8; off; off >>= 1) {
            pl += __shfl_xor(pl, off);
            pr += __shfl_xor(pr, off);
        }
        if (lane == 0) {
            al2_o[node] = make_float2(pl, disn);
            ar_o[node] = pr;
        }
    }
}

// ---------------- output: log_softmax(h @ W2^T + b2) ---------------------------
__global__ __launch_bounds__(256) void k_out(const float* __restrict__ h,
                                             const float* __restrict__ W2,
                                             const float* __restrict__ b2,
                                             float* __restrict__ out, int n) {
    __shared__ float ws[NCLASS * HIDDEN];
    __shared__ float bs[NCLASS];
    const int tid = threadIdx.x;
    for (int i = tid; i < NCLASS * HIDDEN / 4; i += 256)
        ((float4*)ws)[i] = ((const float4*)W2)[i];
    if (tid < NCLASS) bs[tid] = b2[tid];
    __syncthreads();
    int node = blockIdx.x * 256 + tid;
    if (node >= n) return;
    const float* hr = h + (size_t)node * HIDDEN;
    float acc[NCLASS];
#pragma unroll
    for (int c = 0; c < NCLASS; ++c) acc[c] = bs[c];
#pragma unroll
    for (int k0 = 0; k0 < HIDDEN; k0 += 16) {
        float4 h0 = *(const float4*)(hr + k0);
        float4 h1 = *(const float4*)(hr + k0 + 4);
        float4 h2 = *(const float4*)(hr + k0 + 8);
        float4 h3 = *(const float4*)(hr + k0 + 12);
#pragma unroll
        for (int c = 0; c < NCLASS; ++c) {
            const float* w = ws + c * HIDDEN + k0;
            float4 w0 = *(const float4*)(w);
            float4 w1 = *(const float4*)(w + 4);
            float4 w2v = *(const float4*)(w + 8);
            float4 w3 = *(const float4*)(w + 12);
            acc[c] += h0.x * w0.x + h0.y * w0.y + h0.z * w0.z + h0.w * w0.w +
                      h1.x * w1.x + h1.y * w1.y + h1.z * w1.z + h1.w * w1.w +
                      h2.x * w2v.x + h2.y * w2v.y + h2.z * w2v.z + h2.w * w2v.w +
                      h3.x * w3.x + h3.y * w3.y + h3.z * w3.z + h3.w * w3.w;
        }
    }
    float m = -INFINITY;
#pragma unroll
    for (int c = 0; c < NCLASS; ++c) m = fmaxf(m, acc[c]);
    float ssum = 0.f;
#pragma unroll
    for (int c = 0; c < NCLASS; ++c) ssum += expf(acc[c] - m);
    float lse = m + logf(ssum);
    float* orow = out + (size_t)node * NCLASS;
#pragma unroll
    for (int c = 0; c < NCLASS; ++c) orow[c] = acc[c] - lse;
}

extern "C" void kernel_launch(void* const* d_in, const int* in_sizes, int n_in,
                              void* d_out, int out_size, void* d_ws, size_t ws_size,
                              hipStream_t stream) {
    const float* x    = (const float*)d_in[0];
    const int*   ei   = (const int*)d_in[1];
    const float* W1   = (const float*)d_in[2];
    const float* b1   = (const float*)d_in[3];
    const float* W2   = (const float*)d_in[4];
    const float* b2   = (const float*)d_in[5];
    const float* attl = (const float*)d_in[6];
    const float* attr = (const float*)d_in[7];
    const int N = in_sizes[0] / FEAT;
    const int E = in_sizes[1] / 2;
    float* out = (float*)d_out;

    char* p = (char*)d_ws;
    auto take = [&](size_t bytes) {
        void* q = (void*)p;
        p += (bytes + 255) & ~(size_t)255;
        return q;
    };
    float*    h0   = (float*)take((size_t)N * HIDDEN * 4);  // = raw
    float*    h1   = (float*)take((size_t)N * HIDDEN * 4);
    float*    h2   = (float*)take((size_t)N * HIDDEN * 4);
    unsigned* hb0  = (unsigned*)take((size_t)N * 64 * 4);
    unsigned* hb1  = (unsigned*)take((size_t)N * 64 * 4);
    int*      deg  = (int*)take((size_t)N * 4);
    float*    dis  = (float*)take((size_t)N * 4);
    int*      offs = (int*)take((size_t)(N + 1) * 4);
    int*      rank = (int*)take((size_t)E * 4);
    int*      csrc = (int*)take((size_t)E * 4);
    float2*   al2A = (float2*)take((size_t)N * 8);
    float2*   al2B = (float2*)take((size_t)N * 8);
    float*    arA  = (float*)take((size_t)N * 4);
    float*    arB  = (float*)take((size_t)N * 4);
    int*      part = (int*)take(1024);

    hipMemsetAsync(deg, 0, (size_t)N * 4, stream);

    const int nbl = (N + 255) / 256;

    k_degree<<<(E + 2047) / 2048, 256, 0, stream>>>(ei, E, deg, rank);
    k_dis<<<nbl, 256, 0, stream>>>(deg, dis, N);
    k_scan1<<<nbl, 256, 0, stream>>>(deg, offs, part, N);
    k_scan2<<<1, 256, 0, stream>>>(part, nbl);
    k_scan3<<<nbl, 256, 0, stream>>>(offs, part, N, E);
    k_csr_fill<<<(E + 1023) / 1024, 256, 0, stream>>>(ei, E, offs, rank, csrc);

    k_gemm1<<<(N + 127) / 128, 256, 0, stream>>>(x, W1, b1, h0, N);
    k_prep<<<(N + 3) / 4, 256, 0, stream>>>(h0, hb0, attl, attr, dis, al2A, arA, N);

    float*    fout[4] = {h1, h2, h1, h2};
    unsigned* hbin = hb0, *hbout = hb1;
    float2*   alin = al2A, *alout = al2B;
    float*    arin = arA,  *arout = arB;
    for (int l = 0; l < 4; ++l) {
        const float* attl_n = (l < 3) ? (attl + (l + 1) * HIDDEN) : nullptr;
        const float* attr_n = (l < 3) ? (attr + (l + 1) * HIDDEN) : nullptr;
        unsigned* hbo = (l < 3) ? hbout : nullptr;
        k_aggregate<<<(N + 3) / 4, 256, 0, stream>>>(hbin, h0, alin, arin, offs, csrc,
                                                     fout[l], hbo, attl_n, attr_n,
                                                     alout, arout, N);
        unsigned* tb = hbin; hbin = hbout; hbout = tb;
        float2* ta = alin; alin = alout; alout = ta;
        float* tr = arin; arin = arout; arout = tr;
    }

    k_out<<<(N + 255) / 256, 256, 0, stream>>>(h2, W2, b2, out, N);
}